// Round 1
// baseline (2311.734 us; speedup 1.0000x reference)
//
#include <hip/hip_runtime.h>
#include <math.h>

#define B_   2
#define T_   2048
#define C_   1024
#define NH_  16
#define LAT_ 512
#define DHR_ 64
#define M_   (B_*T_)   // 4096

// ---------------------------------------------------------------------------
// Generic tiled fp32 GEMM: Out[M,N] = A[M,K] (row stride lda) @ W[K,N] + bias[N]
// 64x64 output tile per block, K-step 16, 256 threads, 4x4 micro-tile/thread.
// Requires: M%64==0, N%64==0, K%16==0, all pointers 16B-aligned.
// ---------------------------------------------------------------------------
__global__ __launch_bounds__(256)
void gemm_bias(const float* __restrict__ A, int lda,
               const float* __restrict__ W,
               const float* __restrict__ bias,
               float* __restrict__ Out,
               int M, int N, int K)
{
    __shared__ float As[16][64];   // As[k][m] (transposed on store)
    __shared__ float Bs[16][64];   // Bs[k][n]

    const int tid = threadIdx.x;
    const int tx  = tid & 15;
    const int ty  = tid >> 4;
    const int m0  = blockIdx.y << 6;
    const int n0  = blockIdx.x << 6;

    const int arow = tid >> 2;            // 0..63
    const int acg  = (tid & 3) << 2;      // k offset {0,4,8,12}
    const int brow = tid >> 4;            // 0..15 (k)
    const int bcg  = (tid & 15) << 2;     // n offset

    float acc[4][4];
    #pragma unroll
    for (int i = 0; i < 4; ++i)
        #pragma unroll
        for (int j = 0; j < 4; ++j) acc[i][j] = 0.f;

    for (int k0 = 0; k0 < K; k0 += 16) {
        float4 av = *(const float4*)(A + (size_t)(m0 + arow) * lda + k0 + acg);
        float4 bv = *(const float4*)(W + (size_t)(k0 + brow) * N + n0 + bcg);
        As[acg + 0][arow] = av.x;
        As[acg + 1][arow] = av.y;
        As[acg + 2][arow] = av.z;
        As[acg + 3][arow] = av.w;
        *(float4*)(&Bs[brow][bcg]) = bv;
        __syncthreads();

        #pragma unroll
        for (int kk = 0; kk < 16; ++kk) {
            const float4 a = *(const float4*)(&As[kk][ty << 2]);
            const float4 b = *(const float4*)(&Bs[kk][tx << 2]);
            acc[0][0] = fmaf(a.x, b.x, acc[0][0]);
            acc[0][1] = fmaf(a.x, b.y, acc[0][1]);
            acc[0][2] = fmaf(a.x, b.z, acc[0][2]);
            acc[0][3] = fmaf(a.x, b.w, acc[0][3]);
            acc[1][0] = fmaf(a.y, b.x, acc[1][0]);
            acc[1][1] = fmaf(a.y, b.y, acc[1][1]);
            acc[1][2] = fmaf(a.y, b.z, acc[1][2]);
            acc[1][3] = fmaf(a.y, b.w, acc[1][3]);
            acc[2][0] = fmaf(a.z, b.x, acc[2][0]);
            acc[2][1] = fmaf(a.z, b.y, acc[2][1]);
            acc[2][2] = fmaf(a.z, b.z, acc[2][2]);
            acc[2][3] = fmaf(a.z, b.w, acc[2][3]);
            acc[3][0] = fmaf(a.w, b.x, acc[3][0]);
            acc[3][1] = fmaf(a.w, b.y, acc[3][1]);
            acc[3][2] = fmaf(a.w, b.z, acc[3][2]);
            acc[3][3] = fmaf(a.w, b.w, acc[3][3]);
        }
        __syncthreads();
    }

    const float4 bb = *(const float4*)(bias + n0 + (tx << 2));
    #pragma unroll
    for (int i = 0; i < 4; ++i) {
        float4 o;
        o.x = acc[i][0] + bb.x;
        o.y = acc[i][1] + bb.y;
        o.z = acc[i][2] + bb.z;
        o.w = acc[i][3] + bb.w;
        *(float4*)(Out + (size_t)(m0 + (ty << 2) + i) * N + n0 + (tx << 2)) = o;
    }
}

// ---------------------------------------------------------------------------
// In-place interleaved RoPE on Z[M_, D]; pair index pr -> cols (2pr, 2pr+1).
// theta = exp(-2*pr/D * ln(10000)); angle = (t+1)*theta, t = row % T_.
// half = D/2 = 1<<logHalf.
// ---------------------------------------------------------------------------
__global__ void rope_kernel(float* __restrict__ Z, int D, int logHalf, int total)
{
    int idx = blockIdx.x * 256 + threadIdx.x;
    if (idx >= total) return;
    int row = idx >> logHalf;
    int pr  = idx & ((1 << logHalf) - 1);
    int t   = row & (T_ - 1);
    float theta = expf((-2.0f * (float)pr / (float)D) * 9.210340371976184f);
    float ang = (float)(t + 1) * theta;
    float s = sinf(ang);
    float c = cosf(ang);
    float* p = Z + (size_t)row * D + (pr << 1);
    float x1 = p[0];
    float x2 = p[1];
    p[0] = x1 * c - x2 * s;
    p[1] = x2 * c + x1 * s;
}

// ---------------------------------------------------------------------------
// Causal attention, fp32, one thread per query row.
// q-head = [q[mq, h*64 .. +63], qRt[mq, h*64 .. +63]]  (dqk = 128)
// k-head = [kv[mk, h*64 .. +63], kRt[mk, 0..63]]
// v-head = kv[mk, 1024 + h*64 .. +63]                  (dv = 64)
// Block: 256 threads = 256 consecutive query rows of one (b,h).
// K/V staged in LDS in 64-key tiles; lazy online softmax.
// ---------------------------------------------------------------------------
__global__ __launch_bounds__(256)
void attn_kernel(const float* __restrict__ qh,
                 const float* __restrict__ qRt,
                 const float* __restrict__ kv,
                 const float* __restrict__ kRt,
                 float* __restrict__ out)
{
    __shared__ float Ks[64][128];
    __shared__ float Vs[64][64];

    const int tid = threadIdx.x;
    const int bh  = blockIdx.y;
    const int b   = bh >> 4;           // / NH_
    const int h   = bh & 15;
    const int tq  = (blockIdx.x << 8) + tid;   // query position in sequence
    const int mq  = b * T_ + tq;

    float qreg[128];
    #pragma unroll
    for (int d = 0; d < 64; d += 4) {
        float4 v1 = *(const float4*)(qh  + (size_t)mq * C_ + (h << 6) + d);
        qreg[d + 0] = v1.x; qreg[d + 1] = v1.y; qreg[d + 2] = v1.z; qreg[d + 3] = v1.w;
        float4 v2 = *(const float4*)(qRt + (size_t)mq * C_ + (h << 6) + d);
        qreg[64 + d + 0] = v2.x; qreg[64 + d + 1] = v2.y;
        qreg[64 + d + 2] = v2.z; qreg[64 + d + 3] = v2.w;
    }

    float m_run = -1e30f;
    float l_run = 0.f;
    float acc[64];
    #pragma unroll
    for (int d = 0; d < 64; ++d) acc[d] = 0.f;

    const int lastq  = (blockIdx.x << 8) + 255;
    const int ntiles = (lastq >> 6) + 1;

    for (int kt = 0; kt < ntiles; ++kt) {
        const int k0 = kt << 6;

        // ---- stage K tile (64 x 128) and V tile (64 x 64) ----
        #pragma unroll
        for (int r = 0; r < 8; ++r) {
            int flat = tid + (r << 8);
            int j    = flat >> 5;
            int d4   = (flat & 31) << 2;
            const size_t mk = (size_t)(b * T_ + k0 + j);
            float4 vv;
            if (d4 < 64) vv = *(const float4*)(kv  + mk * (2 * C_) + (h << 6) + d4);
            else         vv = *(const float4*)(kRt + mk * DHR_ + (d4 - 64));
            *(float4*)(&Ks[j][d4]) = vv;
        }
        #pragma unroll
        for (int r = 0; r < 4; ++r) {
            int flat = tid + (r << 8);
            int j    = flat >> 4;
            int d4   = (flat & 15) << 2;
            const size_t mk = (size_t)(b * T_ + k0 + j);
            *(float4*)(&Vs[j][d4]) =
                *(const float4*)(kv + mk * (2 * C_) + C_ + (h << 6) + d4);
        }
        __syncthreads();

        const int jmax = min(64, tq - k0 + 1);   // causal; may be <= 0
        for (int j = 0; j < jmax; ++j) {
            float a0 = 0.f, a1 = 0.f, a2 = 0.f, a3 = 0.f;
            #pragma unroll
            for (int d = 0; d < 128; d += 16) {
                float4 k1 = *(const float4*)(&Ks[j][d + 0]);
                float4 k2 = *(const float4*)(&Ks[j][d + 4]);
                float4 k3 = *(const float4*)(&Ks[j][d + 8]);
                float4 k4 = *(const float4*)(&Ks[j][d + 12]);
                a0 = fmaf(qreg[d + 0],  k1.x, a0);
                a1 = fmaf(qreg[d + 1],  k1.y, a1);
                a2 = fmaf(qreg[d + 2],  k1.z, a2);
                a3 = fmaf(qreg[d + 3],  k1.w, a3);
                a0 = fmaf(qreg[d + 4],  k2.x, a0);
                a1 = fmaf(qreg[d + 5],  k2.y, a1);
                a2 = fmaf(qreg[d + 6],  k2.z, a2);
                a3 = fmaf(qreg[d + 7],  k2.w, a3);
                a0 = fmaf(qreg[d + 8],  k3.x, a0);
                a1 = fmaf(qreg[d + 9],  k3.y, a1);
                a2 = fmaf(qreg[d + 10], k3.z, a2);
                a3 = fmaf(qreg[d + 11], k3.w, a3);
                a0 = fmaf(qreg[d + 12], k4.x, a0);
                a1 = fmaf(qreg[d + 13], k4.y, a1);
                a2 = fmaf(qreg[d + 14], k4.z, a2);
                a3 = fmaf(qreg[d + 15], k4.w, a3);
            }
            float s = ((a0 + a1) + (a2 + a3)) * 0.08838834764831845f;

            float p;
            if (s > m_run) {                 // new max: rescale (rare after warmup)
                float alpha = __expf(m_run - s);
                l_run *= alpha;
                #pragma unroll
                for (int d = 0; d < 64; ++d) acc[d] *= alpha;
                m_run = s;
                p = 1.0f;
            } else {
                p = __expf(s - m_run);
            }
            l_run += p;

            #pragma unroll
            for (int d = 0; d < 64; d += 4) {
                float4 vv = *(const float4*)(&Vs[j][d]);
                acc[d + 0] = fmaf(p, vv.x, acc[d + 0]);
                acc[d + 1] = fmaf(p, vv.y, acc[d + 1]);
                acc[d + 2] = fmaf(p, vv.z, acc[d + 2]);
                acc[d + 3] = fmaf(p, vv.w, acc[d + 3]);
            }
        }
        __syncthreads();
    }

    const float inv = 1.0f / l_run;
    #pragma unroll
    for (int d = 0; d < 64; d += 4) {
        float4 o;
        o.x = acc[d + 0] * inv;
        o.y = acc[d + 1] * inv;
        o.z = acc[d + 2] * inv;
        o.w = acc[d + 3] * inv;
        *(float4*)(out + (size_t)mq * C_ + (h << 6) + d) = o;
    }
}

// ---------------------------------------------------------------------------
extern "C" void kernel_launch(void* const* d_in, const int* in_sizes, int n_in,
                              void* d_out, int out_size, void* d_ws, size_t ws_size,
                              hipStream_t stream)
{
    const float* x   = (const float*)d_in[0];
    const float* w1  = (const float*)d_in[1];
    const float* b1  = (const float*)d_in[2];
    const float* wkr = (const float*)d_in[3];
    const float* bkr = (const float*)d_in[4];
    const float* wqr = (const float*)d_in[5];
    const float* bqr = (const float*)d_in[6];
    const float* wkv = (const float*)d_in[7];
    const float* bkv = (const float*)d_in[8];
    const float* wq  = (const float*)d_in[9];
    const float* bq  = (const float*)d_in[10];
    const float* wo  = (const float*)d_in[11];
    const float* bo  = (const float*)d_in[12];
    float* out = (float*)d_out;

    // workspace layout (floats)
    float* ws   = (float*)d_ws;
    float* h    = ws;                 // 4096*1024
    float* qRt  = ws + 4194304;       // 4096*1024
    float* kvb  = ws + 8388608;       // 4096*2048
    float* q    = ws + 16777216;      // 4096*1024
    float* attn = ws + 20971520;      // 4096*1024
    float* kRt  = ws + 25165824;      // 4096*64

    dim3 blk(256);

    // h = x @ w1 + b1                      [4096,1024]
    gemm_bias<<<dim3(16, 64), blk, 0, stream>>>(x, C_, w1, b1, h, M_, 1024, 1024);
    // kRt = h @ wkr + bkr                  [4096,64]
    gemm_bias<<<dim3(1, 64), blk, 0, stream>>>(h, 1024, wkr, bkr, kRt, M_, 64, 1024);
    // qRt = h @ wqr + bqr                  [4096,1024]
    gemm_bias<<<dim3(16, 64), blk, 0, stream>>>(h, 1024, wqr, bqr, qRt, M_, 1024, 1024);
    // rope(kRt, d=64), rope(qRt, d=1024)
    rope_kernel<<<(M_ * 32 + 255) / 256, blk, 0, stream>>>(kRt, 64, 5, M_ * 32);
    rope_kernel<<<(M_ * 512 + 255) / 256, blk, 0, stream>>>(qRt, 1024, 9, M_ * 512);
    // kv = cKV @ wkv + bkv  (cKV = h[:, :512])   [4096,2048]
    gemm_bias<<<dim3(32, 64), blk, 0, stream>>>(h, 1024, wkv, bkv, kvb, M_, 2048, 512);
    // q = cq @ wq + bq      (cq = h[:, 512:])    [4096,1024]
    gemm_bias<<<dim3(16, 64), blk, 0, stream>>>(h + 512, 1024, wq, bq, q, M_, 1024, 512);
    // attention -> attn [4096,1024] (already (B,T,NH,DK) row-major == (B,T,C))
    attn_kernel<<<dim3(8, 32), blk, 0, stream>>>(q, qRt, kvb, kRt, attn);
    // out = attn @ wo + bo                 [4096,1024]
    gemm_bias<<<dim3(16, 64), blk, 0, stream>>>(attn, 1024, wo, bo, out, M_, 1024, 1024);
}

// Round 2
// 867.561 us; speedup vs baseline: 2.6646x; 2.6646x over previous
//
#include <hip/hip_runtime.h>
#include <math.h>

#define B_   2
#define T_   2048
#define C_   1024
#define NH_  16
#define LAT_ 512
#define DHR_ 64
#define M_   (B_*T_)   // 4096

typedef short short8 __attribute__((ext_vector_type(8)));
typedef short short4v __attribute__((ext_vector_type(4)));
typedef float f32x4 __attribute__((ext_vector_type(4)));

__device__ __forceinline__ short f2bf(float f) {
    union { float f; unsigned u; } x; x.f = f;
    unsigned r = x.u + 0x7fffu + ((x.u >> 16) & 1u);
    return (short)(r >> 16);
}

// ---------------------------------------------------------------------------
// Generic tiled fp32 GEMM: Out[M,N] = A[M,K] (row stride lda) @ W[K,N] + bias[N]
// ---------------------------------------------------------------------------
__global__ __launch_bounds__(256)
void gemm_bias(const float* __restrict__ A, int lda,
               const float* __restrict__ W,
               const float* __restrict__ bias,
               float* __restrict__ Out,
               int M, int N, int K)
{
    __shared__ float As[16][64];   // As[k][m] (transposed on store)
    __shared__ float Bs[16][64];   // Bs[k][n]

    const int tid = threadIdx.x;
    const int tx  = tid & 15;
    const int ty  = tid >> 4;
    const int m0  = blockIdx.y << 6;
    const int n0  = blockIdx.x << 6;

    const int arow = tid >> 2;            // 0..63
    const int acg  = (tid & 3) << 2;      // k offset {0,4,8,12}
    const int brow = tid >> 4;            // 0..15 (k)
    const int bcg  = (tid & 15) << 2;     // n offset

    float acc[4][4];
    #pragma unroll
    for (int i = 0; i < 4; ++i)
        #pragma unroll
        for (int j = 0; j < 4; ++j) acc[i][j] = 0.f;

    for (int k0 = 0; k0 < K; k0 += 16) {
        float4 av = *(const float4*)(A + (size_t)(m0 + arow) * lda + k0 + acg);
        float4 bv = *(const float4*)(W + (size_t)(k0 + brow) * N + n0 + bcg);
        As[acg + 0][arow] = av.x;
        As[acg + 1][arow] = av.y;
        As[acg + 2][arow] = av.z;
        As[acg + 3][arow] = av.w;
        *(float4*)(&Bs[brow][bcg]) = bv;
        __syncthreads();

        #pragma unroll
        for (int kk = 0; kk < 16; ++kk) {
            const float4 a = *(const float4*)(&As[kk][ty << 2]);
            const float4 b = *(const float4*)(&Bs[kk][tx << 2]);
            acc[0][0] = fmaf(a.x, b.x, acc[0][0]);
            acc[0][1] = fmaf(a.x, b.y, acc[0][1]);
            acc[0][2] = fmaf(a.x, b.z, acc[0][2]);
            acc[0][3] = fmaf(a.x, b.w, acc[0][3]);
            acc[1][0] = fmaf(a.y, b.x, acc[1][0]);
            acc[1][1] = fmaf(a.y, b.y, acc[1][1]);
            acc[1][2] = fmaf(a.y, b.z, acc[1][2]);
            acc[1][3] = fmaf(a.y, b.w, acc[1][3]);
            acc[2][0] = fmaf(a.z, b.x, acc[2][0]);
            acc[2][1] = fmaf(a.z, b.y, acc[2][1]);
            acc[2][2] = fmaf(a.z, b.z, acc[2][2]);
            acc[2][3] = fmaf(a.z, b.w, acc[2][3]);
            acc[3][0] = fmaf(a.w, b.x, acc[3][0]);
            acc[3][1] = fmaf(a.w, b.y, acc[3][1]);
            acc[3][2] = fmaf(a.w, b.z, acc[3][2]);
            acc[3][3] = fmaf(a.w, b.w, acc[3][3]);
        }
        __syncthreads();
    }

    const float4 bb = *(const float4*)(bias + n0 + (tx << 2));
    #pragma unroll
    for (int i = 0; i < 4; ++i) {
        float4 o;
        o.x = acc[i][0] + bb.x;
        o.y = acc[i][1] + bb.y;
        o.z = acc[i][2] + bb.z;
        o.w = acc[i][3] + bb.w;
        *(float4*)(Out + (size_t)(m0 + (ty << 2) + i) * N + n0 + (tx << 2)) = o;
    }
}

// ---------------------------------------------------------------------------
// In-place interleaved RoPE on Z[M_, D]
// ---------------------------------------------------------------------------
__global__ void rope_kernel(float* __restrict__ Z, int D, int logHalf, int total)
{
    int idx = blockIdx.x * 256 + threadIdx.x;
    if (idx >= total) return;
    int row = idx >> logHalf;
    int pr  = idx & ((1 << logHalf) - 1);
    int t   = row & (T_ - 1);
    float theta = expf((-2.0f * (float)pr / (float)D) * 9.210340371976184f);
    float ang = (float)(t + 1) * theta;
    float s = sinf(ang);
    float c = cosf(ang);
    float* p = Z + (size_t)row * D + (pr << 1);
    float x1 = p[0];
    float x2 = p[1];
    p[0] = x1 * c - x2 * s;
    p[1] = x2 * c + x1 * s;
}

// ---------------------------------------------------------------------------
// MFMA flash attention (bf16 compute, fp32 accum).
// Block: 256 threads = 4 waves; 128 query rows of one (b,h); 64-key tiles.
// Layouts (16x16x32 bf16 MFMA, m89/m120-verified):
//   A-operand: lane holds A[m = lane&15][k = quad*8 + j]
//   B-operand: lane holds B^T row: col n = lane&15, k = quad*8 + j
//   C/D:       lane holds D[row = quad*4 + reg][col = lane&15]
// P round-trips through per-wave LDS (C-layout -> A-layout).
// LDS rows padded +8 bf16 -> only 2-way bank aliasing (free, m136).
// ---------------------------------------------------------------------------
#define KT_   64
#define KROW  136   // 128 + 8 pad (bf16 elems per K row)
#define VROW  72    // 64 + 8
#define PROW  72    // 64 + 8

__global__ __launch_bounds__(256)
void attn_mfma(const float* __restrict__ qh,
               const float* __restrict__ qRt,
               const float* __restrict__ kv,
               const float* __restrict__ kRt,
               float* __restrict__ out)
{
    __shared__ __align__(16) short Ks[64 * KROW];       // [key][d]
    __shared__ __align__(16) short Vt[64 * VROW];       // [dv][key]  (transposed)
    __shared__ __align__(16) short Pst[4 * 32 * PROW];  // per-wave [q][key]

    const int tid  = threadIdx.x;
    const int lane = tid & 63;
    const int ln   = lane & 15;
    const int quad = lane >> 4;
    const int wv   = tid >> 6;
    const int bh   = blockIdx.y;
    const int b    = bh >> 4;
    const int h    = bh & 15;
    const int bT   = b * T_;
    const int q0   = blockIdx.x << 7;     // block's first query
    const int wq0  = q0 + wv * 32;        // wave's first query
    const int wq1  = wq0 + 31;            // wave's last query

    // ---- Q fragments in registers (pre-scaled by 1/sqrt(128)) ----
    const float scale = 0.08838834764831845f;
    short8 aq[2][4];
    #pragma unroll
    for (int mi = 0; mi < 2; ++mi) {
        const size_t row = (size_t)(bT + wq0 + mi * 16 + ln);
        #pragma unroll
        for (int kk = 0; kk < 4; ++kk) {
            const int col = kk * 32 + quad * 8;
            const float* src = (kk < 2)
                ? (qh  + row * C_ + h * 64 + col)
                : (qRt + row * C_ + h * 64 + (col - 64));
            float4 f0 = *(const float4*)(src);
            float4 f1 = *(const float4*)(src + 4);
            short8 v;
            v[0] = f2bf(f0.x * scale); v[1] = f2bf(f0.y * scale);
            v[2] = f2bf(f0.z * scale); v[3] = f2bf(f0.w * scale);
            v[4] = f2bf(f1.x * scale); v[5] = f2bf(f1.y * scale);
            v[6] = f2bf(f1.z * scale); v[7] = f2bf(f1.w * scale);
            aq[mi][kk] = v;
        }
    }

    f32x4 O[2][4];
    float m_run[2][4], l_run[2][4];
    #pragma unroll
    for (int mi = 0; mi < 2; ++mi)
        #pragma unroll
        for (int ni = 0; ni < 4; ++ni) {
            O[mi][ni] = (f32x4){0.f, 0.f, 0.f, 0.f};
            m_run[mi][ni] = -1e30f;   // (indexed [mi][r] below)
            l_run[mi][ni] = 0.f;
        }

    const int ntiles = 2 * blockIdx.x + 2;

    for (int kt = 0; kt < ntiles; ++kt) {
        const int k0    = kt << 6;
        const int kbase = bT + k0;

        // ---- stage K tile [64 x 128] as bf16 ----
        #pragma unroll
        for (int rr = 0; rr < 8; ++rr) {
            int flat = tid + (rr << 8);          // 0..2047 (float4 units)
            int j    = flat >> 5;                // key row
            int c4   = (flat & 31) << 2;         // d offset
            const float* src = (c4 < 64)
                ? (kv  + (size_t)(kbase + j) * (2 * C_) + h * 64 + c4)
                : (kRt + (size_t)(kbase + j) * DHR_ + (c4 - 64));
            float4 f = *(const float4*)src;
            short4v sv;
            sv[0] = f2bf(f.x); sv[1] = f2bf(f.y);
            sv[2] = f2bf(f.z); sv[3] = f2bf(f.w);
            *(short4v*)(&Ks[j * KROW + c4]) = sv;
        }
        // ---- stage V tile transposed [64 dv x 64 key] as bf16 ----
        #pragma unroll
        for (int rr = 0; rr < 4; ++rr) {
            int flat = tid + (rr << 8);          // 0..1023 (float4 units)
            int j    = flat >> 4;                // key row
            int c4   = (flat & 15) << 2;         // dv offset
            float4 f = *(const float4*)(kv + (size_t)(kbase + j) * (2 * C_) + C_ + h * 64 + c4);
            Vt[(c4 + 0) * VROW + j] = f2bf(f.x);
            Vt[(c4 + 1) * VROW + j] = f2bf(f.y);
            Vt[(c4 + 2) * VROW + j] = f2bf(f.z);
            Vt[(c4 + 3) * VROW + j] = f2bf(f.w);
        }
        __syncthreads();

        if (k0 <= wq1) {   // wave-uniform: this tile has at least one valid key
            // ---- S = Q K^T (bf16 MFMA) ----
            f32x4 S[2][4];
            #pragma unroll
            for (int mi = 0; mi < 2; ++mi)
                #pragma unroll
                for (int ni = 0; ni < 4; ++ni)
                    S[mi][ni] = (f32x4){0.f, 0.f, 0.f, 0.f};

            #pragma unroll
            for (int kk = 0; kk < 4; ++kk) {
                #pragma unroll
                for (int ni = 0; ni < 4; ++ni) {
                    short8 bk = *(const short8*)(&Ks[(ni * 16 + ln) * KROW + kk * 32 + quad * 8]);
                    S[0][ni] = __builtin_amdgcn_mfma_f32_16x16x32_bf16(aq[0][kk], bk, S[0][ni], 0, 0, 0);
                    S[1][ni] = __builtin_amdgcn_mfma_f32_16x16x32_bf16(aq[1][kk], bk, S[1][ni], 0, 0, 0);
                }
            }

            const bool full = (k0 + 63) <= wq0;   // no masking needed (wave-uniform)

            // ---- online softmax on C-layout S ----
            #pragma unroll
            for (int mi = 0; mi < 2; ++mi) {
                #pragma unroll
                for (int r = 0; r < 4; ++r) {
                    const int qg = wq0 + mi * 16 + quad * 4 + r;
                    float s0 = S[mi][0][r], s1 = S[mi][1][r];
                    float s2 = S[mi][2][r], s3 = S[mi][3][r];
                    bool v0 = true, v1 = true, v2 = true, v3 = true;
                    if (!full) {
                        v0 = (k0 +  0 + ln) <= qg; if (!v0) s0 = -1e30f;
                        v1 = (k0 + 16 + ln) <= qg; if (!v1) s1 = -1e30f;
                        v2 = (k0 + 32 + ln) <= qg; if (!v2) s2 = -1e30f;
                        v3 = (k0 + 48 + ln) <= qg; if (!v3) s3 = -1e30f;
                    }
                    float rmax = fmaxf(fmaxf(s0, s1), fmaxf(s2, s3));
                    #pragma unroll
                    for (int off = 1; off < 16; off <<= 1)
                        rmax = fmaxf(rmax, __shfl_xor(rmax, off));
                    const float mold = m_run[mi][r];
                    const float mnew = fmaxf(mold, rmax);
                    const float alpha = __expf(mold - mnew);
                    m_run[mi][r] = mnew;
                    float p0 = __expf(s0 - mnew);
                    float p1 = __expf(s1 - mnew);
                    float p2 = __expf(s2 - mnew);
                    float p3 = __expf(s3 - mnew);
                    if (!full) {
                        if (!v0) p0 = 0.f;
                        if (!v1) p1 = 0.f;
                        if (!v2) p2 = 0.f;
                        if (!v3) p3 = 0.f;
                    }
                    float rsum = (p0 + p1) + (p2 + p3);
                    #pragma unroll
                    for (int off = 1; off < 16; off <<= 1)
                        rsum += __shfl_xor(rsum, off);
                    l_run[mi][r] = l_run[mi][r] * alpha + rsum;
                    O[mi][0][r] *= alpha;
                    O[mi][1][r] *= alpha;
                    O[mi][2][r] *= alpha;
                    O[mi][3][r] *= alpha;
                    const int prow = (wv * 32 + mi * 16 + quad * 4 + r) * PROW;
                    Pst[prow +  0 + ln] = f2bf(p0);
                    Pst[prow + 16 + ln] = f2bf(p1);
                    Pst[prow + 32 + ln] = f2bf(p2);
                    Pst[prow + 48 + ln] = f2bf(p3);
                }
            }

            asm volatile("s_waitcnt lgkmcnt(0)" ::: "memory");

            // ---- O += P V (bf16 MFMA) ----
            #pragma unroll
            for (int ks = 0; ks < 2; ++ks) {
                short8 ap0 = *(const short8*)(&Pst[(wv * 32 +  0 + ln) * PROW + ks * 32 + quad * 8]);
                short8 ap1 = *(const short8*)(&Pst[(wv * 32 + 16 + ln) * PROW + ks * 32 + quad * 8]);
                #pragma unroll
                for (int ni = 0; ni < 4; ++ni) {
                    short8 bv = *(const short8*)(&Vt[(ni * 16 + ln) * VROW + ks * 32 + quad * 8]);
                    O[0][ni] = __builtin_amdgcn_mfma_f32_16x16x32_bf16(ap0, bv, O[0][ni], 0, 0, 0);
                    O[1][ni] = __builtin_amdgcn_mfma_f32_16x16x32_bf16(ap1, bv, O[1][ni], 0, 0, 0);
                }
            }
        }
        __syncthreads();
    }

    // ---- epilogue: out[q][h*64+dv] = O / l ----
    #pragma unroll
    for (int mi = 0; mi < 2; ++mi) {
        #pragma unroll
        for (int r = 0; r < 4; ++r) {
            const float inv = 1.0f / l_run[mi][r];
            const size_t qg = (size_t)(bT + wq0 + mi * 16 + quad * 4 + r);
            #pragma unroll
            for (int ni = 0; ni < 4; ++ni)
                out[qg * C_ + h * 64 + ni * 16 + ln] = O[mi][ni][r] * inv;
        }
    }
}

// ---------------------------------------------------------------------------
extern "C" void kernel_launch(void* const* d_in, const int* in_sizes, int n_in,
                              void* d_out, int out_size, void* d_ws, size_t ws_size,
                              hipStream_t stream)
{
    const float* x   = (const float*)d_in[0];
    const float* w1  = (const float*)d_in[1];
    const float* b1  = (const float*)d_in[2];
    const float* wkr = (const float*)d_in[3];
    const float* bkr = (const float*)d_in[4];
    const float* wqr = (const float*)d_in[5];
    const float* bqr = (const float*)d_in[6];
    const float* wkv = (const float*)d_in[7];
    const float* bkv = (const float*)d_in[8];
    const float* wq  = (const float*)d_in[9];
    const float* bq  = (const float*)d_in[10];
    const float* wo  = (const float*)d_in[11];
    const float* bo  = (const float*)d_in[12];
    float* out = (float*)d_out;

    // workspace layout (floats)
    float* ws   = (float*)d_ws;
    float* h    = ws;                 // 4096*1024
    float* qRt  = ws + 4194304;       // 4096*1024
    float* kvb  = ws + 8388608;       // 4096*2048
    float* q    = ws + 16777216;      // 4096*1024
    float* attn = ws + 20971520;      // 4096*1024
    float* kRt  = ws + 25165824;      // 4096*64

    dim3 blk(256);

    gemm_bias<<<dim3(16, 64), blk, 0, stream>>>(x, C_, w1, b1, h, M_, 1024, 1024);
    gemm_bias<<<dim3(1, 64), blk, 0, stream>>>(h, 1024, wkr, bkr, kRt, M_, 64, 1024);
    gemm_bias<<<dim3(16, 64), blk, 0, stream>>>(h, 1024, wqr, bqr, qRt, M_, 1024, 1024);
    rope_kernel<<<(M_ * 32 + 255) / 256, blk, 0, stream>>>(kRt, 64, 5, M_ * 32);
    rope_kernel<<<(M_ * 512 + 255) / 256, blk, 0, stream>>>(qRt, 1024, 9, M_ * 512);
    gemm_bias<<<dim3(32, 64), blk, 0, stream>>>(h, 1024, wkv, bkv, kvb, M_, 2048, 512);
    gemm_bias<<<dim3(16, 64), blk, 0, stream>>>(h + 512, 1024, wq, bq, q, M_, 1024, 512);
    attn_mfma<<<dim3(16, 32), blk, 0, stream>>>(q, qRt, kvb, kRt, attn);
    gemm_bias<<<dim3(16, 64), blk, 0, stream>>>(attn, 1024, wo, bo, out, M_, 1024, 1024);
}

// Round 3
// 464.209 us; speedup vs baseline: 4.9799x; 1.8689x over previous
//
#include <hip/hip_runtime.h>
#include <math.h>
#include <stdint.h>

#define B_   2
#define T_   2048
#define C_   1024
#define NH_  16
#define LAT_ 512
#define DHR_ 64
#define M_   (B_*T_)   // 4096

typedef unsigned short u16;
typedef short short8 __attribute__((ext_vector_type(8)));
typedef short short4v __attribute__((ext_vector_type(4)));
typedef float f32x4 __attribute__((ext_vector_type(4)));

__device__ __forceinline__ u16 f2bf(float f) {
    union { float f; unsigned u; } x; x.f = f;
    unsigned r = x.u + 0x7fffu + ((x.u >> 16) & 1u);
    return (u16)(r >> 16);
}
__device__ __forceinline__ float bf2f(u16 v) {
    union { unsigned u; float f; } x; x.u = ((unsigned)v) << 16;
    return x.f;
}

// async global->LDS, 16B per lane (m97: the single biggest GEMM lever)
__device__ __forceinline__ void gl_lds16(const void* g, void* l) {
    auto* gp = reinterpret_cast<const __attribute__((address_space(1))) unsigned*>(
        reinterpret_cast<uintptr_t>(g));
    auto* lp = reinterpret_cast<__attribute__((address_space(3))) unsigned*>(
        reinterpret_cast<uintptr_t>(l));
    __builtin_amdgcn_global_load_lds(gp, lp, 16, 0, 0);
}

// ---------------------------------------------------------------------------
// fp32 -> bf16 elementwise (x conversion).  n = elems/4.
// ---------------------------------------------------------------------------
__global__ void cvt_f2b(const float* __restrict__ X, u16* __restrict__ Xb, int n4)
{
    int i = blockIdx.x * 256 + threadIdx.x;
    if (i >= n4) return;
    float4 v = ((const float4*)X)[i];
    short4v s;
    s[0] = f2bf(v.x); s[1] = f2bf(v.y); s[2] = f2bf(v.z); s[3] = f2bf(v.w);
    ((short4v*)Xb)[i] = s;
}

// ---------------------------------------------------------------------------
// W[K,N] fp32 -> Wt[N,K] bf16 (32x32 tiles, K%32==0, N%32==0)
// ---------------------------------------------------------------------------
__global__ __launch_bounds__(256)
void transpose_cvt(const float* __restrict__ W, u16* __restrict__ Wt, int K, int N)
{
    __shared__ float t[32][33];
    const int tx = threadIdx.x & 31;
    const int ty = threadIdx.x >> 5;       // 0..7
    const int n0 = blockIdx.x << 5;
    const int k0 = blockIdx.y << 5;
    #pragma unroll
    for (int r = 0; r < 4; ++r) {
        int row = ty + (r << 3);
        t[row][tx] = W[(size_t)(k0 + row) * N + n0 + tx];
    }
    __syncthreads();
    #pragma unroll
    for (int r = 0; r < 4; ++r) {
        int row = ty + (r << 3);
        Wt[(size_t)(n0 + row) * K + k0 + tx] = f2bf(t[tx][row]);
    }
}

// ---------------------------------------------------------------------------
// bf16 MFMA GEMM (m97 structure): Out[M,N] = A[M,K](lda) @ Bt[N,K]^T + bias
// Tile BM x BN (BM=WGM*64, BN=WGN*64), BK=32, 256 thr = 4 waves, each wave
// computes 64x64 via 4x4 grid of 16x16x32 MFMAs. Staging via global_load_lds
// (16B/lane) into unpadded [row][32] LDS (layout required by gl_lds).
// ---------------------------------------------------------------------------
template<int WGM, int WGN, bool OUTF32>
__global__ __launch_bounds__(256)
void gemm_mfma(const u16* __restrict__ A, int lda,
               const u16* __restrict__ Bt,
               const float* __restrict__ bias,
               void* __restrict__ Out,
               int N, int K)
{
    constexpr int BM = WGM * 64;
    constexpr int BN = WGN * 64;
    __shared__ __align__(16) u16 As[BM * 32];
    __shared__ __align__(16) u16 Bs[BN * 32];

    const int tid  = threadIdx.x;
    const int lane = tid & 63;
    const int ln   = lane & 15;
    const int quad = lane >> 4;
    const int wv   = tid >> 6;
    const int wm   = (wv % WGM) << 6;
    const int wn   = (wv / WGM) << 6;
    const int m0   = blockIdx.y * BM;
    const int n0   = blockIdx.x * BN;

    f32x4 acc[4][4];
    #pragma unroll
    for (int i = 0; i < 4; ++i)
        #pragma unroll
        for (int j = 0; j < 4; ++j) acc[i][j] = (f32x4){0.f, 0.f, 0.f, 0.f};

    for (int k0 = 0; k0 < K; k0 += 32) {
        #pragma unroll
        for (int it = 0; it < BM / 64; ++it) {
            int flat = it * 256 + tid;
            int row  = flat >> 2;
            int ko   = (flat & 3) << 3;
            gl_lds16(A + (size_t)(m0 + row) * lda + k0 + ko, &As[flat * 8]);
        }
        #pragma unroll
        for (int it = 0; it < BN / 64; ++it) {
            int flat = it * 256 + tid;
            int row  = flat >> 2;
            int ko   = (flat & 3) << 3;
            gl_lds16(Bt + (size_t)(n0 + row) * K + k0 + ko, &Bs[flat * 8]);
        }
        __syncthreads();

        short8 af[4], bf[4];
        #pragma unroll
        for (int mi = 0; mi < 4; ++mi)
            af[mi] = *(const short8*)(&As[(wm + mi * 16 + ln) * 32 + quad * 8]);
        #pragma unroll
        for (int ni = 0; ni < 4; ++ni)
            bf[ni] = *(const short8*)(&Bs[(wn + ni * 16 + ln) * 32 + quad * 8]);
        #pragma unroll
        for (int mi = 0; mi < 4; ++mi)
            #pragma unroll
            for (int ni = 0; ni < 4; ++ni)
                acc[mi][ni] = __builtin_amdgcn_mfma_f32_16x16x32_bf16(af[mi], bf[ni], acc[mi][ni], 0, 0, 0);
        __syncthreads();
    }

    float bb[4];
    #pragma unroll
    for (int ni = 0; ni < 4; ++ni) bb[ni] = bias[n0 + wn + ni * 16 + ln];

    #pragma unroll
    for (int mi = 0; mi < 4; ++mi) {
        #pragma unroll
        for (int r = 0; r < 4; ++r) {
            const size_t row = (size_t)(m0 + wm + mi * 16 + quad * 4 + r);
            #pragma unroll
            for (int ni = 0; ni < 4; ++ni) {
                float v = acc[mi][ni][r] + bb[ni];
                const size_t idx = row * N + n0 + wn + ni * 16 + ln;
                if (OUTF32) ((float*)Out)[idx] = v;
                else        ((u16*)Out)[idx]  = f2bf(v);
            }
        }
    }
}

// ---------------------------------------------------------------------------
// In-place interleaved RoPE on bf16 Z[M_, D]
// ---------------------------------------------------------------------------
__global__ void rope_bf(u16* __restrict__ Z, int D, int logHalf, int total)
{
    int idx = blockIdx.x * 256 + threadIdx.x;
    if (idx >= total) return;
    int row = idx >> logHalf;
    int pr  = idx & ((1 << logHalf) - 1);
    int t   = row & (T_ - 1);
    float theta = expf((-2.0f * (float)pr / (float)D) * 9.210340371976184f);
    float ang = (float)(t + 1) * theta;
    float s = sinf(ang);
    float c = cosf(ang);
    u16* p = Z + (size_t)row * D + (pr << 1);
    float x1 = bf2f(p[0]);
    float x2 = bf2f(p[1]);
    p[0] = f2bf(x1 * c - x2 * s);
    p[1] = f2bf(x2 * c + x1 * s);
}

// ---------------------------------------------------------------------------
// MFMA flash attention, bf16 in (q/qRt/kv/kRt), bf16 out.
// ---------------------------------------------------------------------------
#define KROW  136   // 128 + 8 pad
#define VROW  72    // 64 + 8
#define PROW  72    // 64 + 8

__global__ __launch_bounds__(256)
void attn_mfma(const u16* __restrict__ qh,
               const u16* __restrict__ qRt,
               const u16* __restrict__ kv,
               const u16* __restrict__ kRt,
               u16* __restrict__ out)
{
    __shared__ __align__(16) u16 Ks[64 * KROW];       // [key][d]
    __shared__ __align__(16) u16 Vt[64 * VROW];       // [dv][key]
    __shared__ __align__(16) u16 Pst[4 * 32 * PROW];  // per-wave [q][key]

    const int tid  = threadIdx.x;
    const int lane = tid & 63;
    const int ln   = lane & 15;
    const int quad = lane >> 4;
    const int wv   = tid >> 6;
    const int bh   = blockIdx.y;
    const int b    = bh >> 4;
    const int h    = bh & 15;
    const int bT   = b * T_;
    const int q0   = blockIdx.x << 7;
    const int wq0  = q0 + wv * 32;
    const int wq1  = wq0 + 31;
    const float scale = 0.08838834764831845f;

    short8 aq[2][4];
    #pragma unroll
    for (int mi = 0; mi < 2; ++mi) {
        const size_t row = (size_t)(bT + wq0 + mi * 16 + ln);
        #pragma unroll
        for (int kk = 0; kk < 4; ++kk) {
            const int col = kk * 32 + quad * 8;
            const u16* src = (kk < 2)
                ? (qh  + row * C_ + h * 64 + col)
                : (qRt + row * C_ + h * 64 + (col - 64));
            aq[mi][kk] = *(const short8*)src;
        }
    }

    f32x4 O[2][4];
    float m_run[2][4], l_run[2][4];
    #pragma unroll
    for (int mi = 0; mi < 2; ++mi)
        #pragma unroll
        for (int ni = 0; ni < 4; ++ni) {
            O[mi][ni] = (f32x4){0.f, 0.f, 0.f, 0.f};
            m_run[mi][ni] = -1e30f;
            l_run[mi][ni] = 0.f;
        }

    const int ntiles = 2 * blockIdx.x + 2;

    for (int kt = 0; kt < ntiles; ++kt) {
        const int k0    = kt << 6;
        const int kbase = bT + k0;

        // ---- stage K tile [64 x 128] ----
        #pragma unroll
        for (int it = 0; it < 4; ++it) {
            int flat = tid + (it << 8);        // 0..1023, 8 elems each
            int j    = flat >> 4;
            int c8   = (flat & 15) << 3;
            const u16* src = (c8 < 64)
                ? (kv  + (size_t)(kbase + j) * (2 * C_) + h * 64 + c8)
                : (kRt + (size_t)(kbase + j) * DHR_ + (c8 - 64));
            *(short8*)(&Ks[j * KROW + c8]) = *(const short8*)src;
        }
        // ---- stage V tile transposed [dv][key] ----
        #pragma unroll
        for (int it = 0; it < 2; ++it) {
            int flat = tid + (it << 8);        // 0..511, 8 elems each
            int j    = flat >> 3;
            int c8   = (flat & 7) << 3;
            short8 v = *(const short8*)(kv + (size_t)(kbase + j) * (2 * C_) + C_ + h * 64 + c8);
            #pragma unroll
            for (int e = 0; e < 8; ++e)
                Vt[(c8 + e) * VROW + j] = v[e];
        }
        __syncthreads();

        if (k0 <= wq1) {
            f32x4 S[2][4];
            #pragma unroll
            for (int mi = 0; mi < 2; ++mi)
                #pragma unroll
                for (int ni = 0; ni < 4; ++ni)
                    S[mi][ni] = (f32x4){0.f, 0.f, 0.f, 0.f};

            #pragma unroll
            for (int kk = 0; kk < 4; ++kk) {
                #pragma unroll
                for (int ni = 0; ni < 4; ++ni) {
                    short8 bk = *(const short8*)(&Ks[(ni * 16 + ln) * KROW + kk * 32 + quad * 8]);
                    S[0][ni] = __builtin_amdgcn_mfma_f32_16x16x32_bf16(aq[0][kk], bk, S[0][ni], 0, 0, 0);
                    S[1][ni] = __builtin_amdgcn_mfma_f32_16x16x32_bf16(aq[1][kk], bk, S[1][ni], 0, 0, 0);
                }
            }

            const bool full = (k0 + 63) <= wq0;

            #pragma unroll
            for (int mi = 0; mi < 2; ++mi) {
                #pragma unroll
                for (int r = 0; r < 4; ++r) {
                    const int qg = wq0 + mi * 16 + quad * 4 + r;
                    float s0 = S[mi][0][r] * scale, s1 = S[mi][1][r] * scale;
                    float s2 = S[mi][2][r] * scale, s3 = S[mi][3][r] * scale;
                    bool v0 = true, v1 = true, v2 = true, v3 = true;
                    if (!full) {
                        v0 = (k0 +  0 + ln) <= qg; if (!v0) s0 = -1e30f;
                        v1 = (k0 + 16 + ln) <= qg; if (!v1) s1 = -1e30f;
                        v2 = (k0 + 32 + ln) <= qg; if (!v2) s2 = -1e30f;
                        v3 = (k0 + 48 + ln) <= qg; if (!v3) s3 = -1e30f;
                    }
                    float rmax = fmaxf(fmaxf(s0, s1), fmaxf(s2, s3));
                    #pragma unroll
                    for (int off = 1; off < 16; off <<= 1)
                        rmax = fmaxf(rmax, __shfl_xor(rmax, off));
                    const float mold = m_run[mi][r];
                    const float mnew = fmaxf(mold, rmax);
                    const float alpha = __expf(mold - mnew);
                    m_run[mi][r] = mnew;
                    float p0 = __expf(s0 - mnew);
                    float p1 = __expf(s1 - mnew);
                    float p2 = __expf(s2 - mnew);
                    float p3 = __expf(s3 - mnew);
                    if (!full) {
                        if (!v0) p0 = 0.f;
                        if (!v1) p1 = 0.f;
                        if (!v2) p2 = 0.f;
                        if (!v3) p3 = 0.f;
                    }
                    float rsum = (p0 + p1) + (p2 + p3);
                    #pragma unroll
                    for (int off = 1; off < 16; off <<= 1)
                        rsum += __shfl_xor(rsum, off);
                    l_run[mi][r] = l_run[mi][r] * alpha + rsum;
                    O[mi][0][r] *= alpha;
                    O[mi][1][r] *= alpha;
                    O[mi][2][r] *= alpha;
                    O[mi][3][r] *= alpha;
                    const int prow = (wv * 32 + mi * 16 + quad * 4 + r) * PROW;
                    Pst[prow +  0 + ln] = f2bf(p0);
                    Pst[prow + 16 + ln] = f2bf(p1);
                    Pst[prow + 32 + ln] = f2bf(p2);
                    Pst[prow + 48 + ln] = f2bf(p3);
                }
            }

            asm volatile("s_waitcnt lgkmcnt(0)" ::: "memory");

            #pragma unroll
            for (int ks = 0; ks < 2; ++ks) {
                short8 ap0 = *(const short8*)(&Pst[(wv * 32 +  0 + ln) * PROW + ks * 32 + quad * 8]);
                short8 ap1 = *(const short8*)(&Pst[(wv * 32 + 16 + ln) * PROW + ks * 32 + quad * 8]);
                #pragma unroll
                for (int ni = 0; ni < 4; ++ni) {
                    short8 bv = *(const short8*)(&Vt[(ni * 16 + ln) * VROW + ks * 32 + quad * 8]);
                    O[0][ni] = __builtin_amdgcn_mfma_f32_16x16x32_bf16(ap0, bv, O[0][ni], 0, 0, 0);
                    O[1][ni] = __builtin_amdgcn_mfma_f32_16x16x32_bf16(ap1, bv, O[1][ni], 0, 0, 0);
                }
            }
        }
        __syncthreads();
    }

    #pragma unroll
    for (int mi = 0; mi < 2; ++mi) {
        #pragma unroll
        for (int r = 0; r < 4; ++r) {
            const float inv = 1.0f / l_run[mi][r];
            const size_t qg = (size_t)(bT + wq0 + mi * 16 + quad * 4 + r);
            #pragma unroll
            for (int ni = 0; ni < 4; ++ni)
                out[qg * C_ + h * 64 + ni * 16 + ln] = f2bf(O[mi][ni][r] * inv);
        }
    }
}

// ---------------------------------------------------------------------------
extern "C" void kernel_launch(void* const* d_in, const int* in_sizes, int n_in,
                              void* d_out, int out_size, void* d_ws, size_t ws_size,
                              hipStream_t stream)
{
    const float* x   = (const float*)d_in[0];
    const float* w1  = (const float*)d_in[1];
    const float* b1  = (const float*)d_in[2];
    const float* wkr = (const float*)d_in[3];
    const float* bkr = (const float*)d_in[4];
    const float* wqr = (const float*)d_in[5];
    const float* bqr = (const float*)d_in[6];
    const float* wkv = (const float*)d_in[7];
    const float* bkv = (const float*)d_in[8];
    const float* wq  = (const float*)d_in[9];
    const float* bq  = (const float*)d_in[10];
    const float* wo  = (const float*)d_in[11];
    const float* bo  = (const float*)d_in[12];
    float* out = (float*)d_out;

    // workspace layout (u16 units)
    u16* ws    = (u16*)d_ws;
    u16* xb    = ws;                   // 4096*1024
    u16* hb    = xb    + 4194304;      // 4096*1024
    u16* qRtb  = hb    + 4194304;      // 4096*1024
    u16* qb    = qRtb  + 4194304;      // 4096*1024
    u16* kvbb  = qb    + 4194304;      // 4096*2048
    u16* kRtb  = kvbb  + 8388608;      // 4096*64
    u16* attnb = kRtb  + 262144;       // 4096*1024
    u16* w1t   = attnb + 4194304;      // 1024*1024
    u16* wqrt  = w1t   + 1048576;      // 1024*1024
    u16* wkvt  = wqrt  + 1048576;      // 2048*512
    u16* wqt   = wkvt  + 1048576;      // 1024*512
    u16* wot   = wqt   + 524288;       // 1024*1024
    u16* wkrt  = wot   + 1048576;      // 64*1024

    dim3 blk(256);

    // prep: conversions + weight transposes
    cvt_f2b<<<4096, blk, 0, stream>>>(x, xb, M_ * C_ / 4);
    transpose_cvt<<<dim3(32, 32), blk, 0, stream>>>(w1,  w1t,  1024, 1024);
    transpose_cvt<<<dim3( 2, 32), blk, 0, stream>>>(wkr, wkrt, 1024,   64);
    transpose_cvt<<<dim3(32, 32), blk, 0, stream>>>(wqr, wqrt, 1024, 1024);
    transpose_cvt<<<dim3(64, 16), blk, 0, stream>>>(wkv, wkvt,  512, 2048);
    transpose_cvt<<<dim3(32, 16), blk, 0, stream>>>(wq,  wqt,   512, 1024);
    transpose_cvt<<<dim3(32, 32), blk, 0, stream>>>(wo,  wot,  1024, 1024);

    // h = x @ w1 + b1            [4096,1024] bf16
    gemm_mfma<2, 2, false><<<dim3(8, 32), blk, 0, stream>>>(xb, 1024, w1t, b1, hb, 1024, 1024);
    // kRt = h @ wkr + bkr        [4096,64]
    gemm_mfma<4, 1, false><<<dim3(1, 16), blk, 0, stream>>>(hb, 1024, wkrt, bkr, kRtb, 64, 1024);
    // qRt = h @ wqr + bqr        [4096,1024]
    gemm_mfma<2, 2, false><<<dim3(8, 32), blk, 0, stream>>>(hb, 1024, wqrt, bqr, qRtb, 1024, 1024);
    // rope
    rope_bf<<<(M_ * 32 + 255) / 256, blk, 0, stream>>>(kRtb, 64, 5, M_ * 32);
    rope_bf<<<(M_ * 512 + 255) / 256, blk, 0, stream>>>(qRtb, 1024, 9, M_ * 512);
    // kv = h[:, :512] @ wkv + bkv   [4096,2048]
    gemm_mfma<2, 2, false><<<dim3(16, 32), blk, 0, stream>>>(hb, 1024, wkvt, bkv, kvbb, 2048, 512);
    // q = h[:, 512:] @ wq + bq      [4096,1024]
    gemm_mfma<2, 2, false><<<dim3(8, 32), blk, 0, stream>>>(hb + 512, 1024, wqt, bq, qb, 1024, 512);
    // attention
    attn_mfma<<<dim3(16, 32), blk, 0, stream>>>(qb, qRtb, kvbb, kRtb, attnb);
    // out = attn @ wo + bo          [4096,1024] fp32
    gemm_mfma<2, 2, true><<<dim3(8, 32), blk, 0, stream>>>(attnb, 1024, wot, bo, out, 1024, 1024);
}

// Round 4
// 336.431 us; speedup vs baseline: 6.8713x; 1.3798x over previous
//
#include <hip/hip_runtime.h>
#include <math.h>
#include <stdint.h>

#define B_   2
#define T_   2048
#define C_   1024
#define NH_  16
#define LAT_ 512
#define DHR_ 64
#define M_   (B_*T_)   // 4096

typedef unsigned short u16;
typedef short short8 __attribute__((ext_vector_type(8)));
typedef short short4v __attribute__((ext_vector_type(4)));
typedef float f32x4 __attribute__((ext_vector_type(4)));

__device__ __forceinline__ u16 f2bf(float f) {
    union { float f; unsigned u; } x; x.f = f;
    unsigned r = x.u + 0x7fffu + ((x.u >> 16) & 1u);
    return (u16)(r >> 16);
}
__device__ __forceinline__ float bf2f(u16 v) {
    union { unsigned u; float f; } x; x.u = ((unsigned)v) << 16;
    return x.f;
}

// async global->LDS, 16B per lane (m97)
__device__ __forceinline__ void gl_lds16(const void* g, void* l) {
    auto* gp = reinterpret_cast<const __attribute__((address_space(1))) unsigned*>(
        reinterpret_cast<uintptr_t>(g));
    auto* lp = reinterpret_cast<__attribute__((address_space(3))) unsigned*>(
        reinterpret_cast<uintptr_t>(l));
    __builtin_amdgcn_global_load_lds(gp, lp, 16, 0, 0);
}

// ---------------------------------------------------------------------------
__global__ void cvt_f2b(const float* __restrict__ X, u16* __restrict__ Xb, int n4)
{
    int i = blockIdx.x * 256 + threadIdx.x;
    if (i >= n4) return;
    float4 v = ((const float4*)X)[i];
    short4v s;
    s[0] = f2bf(v.x); s[1] = f2bf(v.y); s[2] = f2bf(v.z); s[3] = f2bf(v.w);
    ((short4v*)Xb)[i] = s;
}

// W[K,N] fp32 -> Wt[N,K] bf16
__global__ __launch_bounds__(256)
void transpose_cvt(const float* __restrict__ W, u16* __restrict__ Wt, int K, int N)
{
    __shared__ float t[32][33];
    const int tx = threadIdx.x & 31;
    const int ty = threadIdx.x >> 5;
    const int n0 = blockIdx.x << 5;
    const int k0 = blockIdx.y << 5;
    #pragma unroll
    for (int r = 0; r < 4; ++r) {
        int row = ty + (r << 3);
        t[row][tx] = W[(size_t)(k0 + row) * N + n0 + tx];
    }
    __syncthreads();
    #pragma unroll
    for (int r = 0; r < 4; ++r) {
        int row = ty + (r << 3);
        Wt[(size_t)(n0 + row) * K + k0 + tx] = f2bf(t[tx][row]);
    }
}

__global__ void concat_bias(const float* __restrict__ bqr,
                            const float* __restrict__ bkr,
                            float* __restrict__ bqk)
{
    int i = blockIdx.x * 256 + threadIdx.x;
    if (i >= 1152) return;
    float v;
    if (i < 1024)      v = bqr[i];
    else if (i < 1088) v = bkr[i - 1024];
    else               v = 0.f;
    bqk[i] = v;
}

// ---------------------------------------------------------------------------
// bf16 MFMA GEMM, double-buffered LDS (explicit dbuf pays off at 1 block/CU).
// Out[M,N] = A[M,K](lda) @ Bt[N,K]^T + bias.  BK=32, 256 thr = 4 waves,
// wave computes 64x64 via 4x4 of 16x16x32 MFMAs.
// ---------------------------------------------------------------------------
template<int WGM, int WGN, bool OUTF32>
__global__ __launch_bounds__(256)
void gemm_mfma(const u16* __restrict__ A, int lda,
               const u16* __restrict__ Bt,
               const float* __restrict__ bias,
               void* __restrict__ Out,
               int N, int K)
{
    constexpr int BM = WGM * 64;
    constexpr int BN = WGN * 64;
    __shared__ __align__(16) u16 As[2][BM * 32];
    __shared__ __align__(16) u16 Bs[2][BN * 32];

    const int tid  = threadIdx.x;
    const int lane = tid & 63;
    const int ln   = lane & 15;
    const int quad = lane >> 4;
    const int wv   = tid >> 6;
    const int wm   = (wv % WGM) << 6;
    const int wn   = (wv / WGM) << 6;
    const int m0   = blockIdx.y * BM;
    const int n0   = blockIdx.x * BN;

    f32x4 acc[4][4];
    #pragma unroll
    for (int i = 0; i < 4; ++i)
        #pragma unroll
        for (int j = 0; j < 4; ++j) acc[i][j] = (f32x4){0.f, 0.f, 0.f, 0.f};

    auto stage = [&](int buf, int k0) {
        #pragma unroll
        for (int it = 0; it < BM / 64; ++it) {
            int flat = it * 256 + tid;
            int row  = flat >> 2;
            int ko   = (flat & 3) << 3;
            gl_lds16(A + (size_t)(m0 + row) * lda + k0 + ko, &As[buf][flat * 8]);
        }
        #pragma unroll
        for (int it = 0; it < BN / 64; ++it) {
            int flat = it * 256 + tid;
            int row  = flat >> 2;
            int ko   = (flat & 3) << 3;
            gl_lds16(Bt + (size_t)(n0 + row) * K + k0 + ko, &Bs[buf][flat * 8]);
        }
    };

    stage(0, 0);
    __syncthreads();

    int buf = 0;
    for (int k0 = 0; k0 < K; k0 += 32) {
        if (k0 + 32 < K) stage(buf ^ 1, k0 + 32);   // async prefetch, in flight

        short8 af[4], bfv[4];
        #pragma unroll
        for (int mi = 0; mi < 4; ++mi)
            af[mi] = *(const short8*)(&As[buf][(wm + mi * 16 + ln) * 32 + quad * 8]);
        #pragma unroll
        for (int ni = 0; ni < 4; ++ni)
            bfv[ni] = *(const short8*)(&Bs[buf][(wn + ni * 16 + ln) * 32 + quad * 8]);
        #pragma unroll
        for (int mi = 0; mi < 4; ++mi)
            #pragma unroll
            for (int ni = 0; ni < 4; ++ni)
                acc[mi][ni] = __builtin_amdgcn_mfma_f32_16x16x32_bf16(af[mi], bfv[ni], acc[mi][ni], 0, 0, 0);

        __syncthreads();   // drains prefetch (vmcnt) + publishes next buf
        buf ^= 1;
    }

    float bb[4];
    #pragma unroll
    for (int ni = 0; ni < 4; ++ni) bb[ni] = bias[n0 + wn + ni * 16 + ln];

    #pragma unroll
    for (int mi = 0; mi < 4; ++mi) {
        #pragma unroll
        for (int r = 0; r < 4; ++r) {
            const size_t row = (size_t)(m0 + wm + mi * 16 + quad * 4 + r);
            #pragma unroll
            for (int ni = 0; ni < 4; ++ni) {
                float v = acc[mi][ni][r] + bb[ni];
                const size_t idx = row * N + n0 + wn + ni * 16 + ln;
                if (OUTF32) ((float*)Out)[idx] = v;
                else        ((u16*)Out)[idx]  = f2bf(v);
            }
        }
    }
}

// ---------------------------------------------------------------------------
// In-place interleaved RoPE on bf16 Z[M_, D], row stride `stride`
// ---------------------------------------------------------------------------
__global__ void rope_bf(u16* __restrict__ Z, int stride, int D, int logHalf, int total)
{
    int idx = blockIdx.x * 256 + threadIdx.x;
    if (idx >= total) return;
    int row = idx >> logHalf;
    int pr  = idx & ((1 << logHalf) - 1);
    int t   = row & (T_ - 1);
    float theta = expf((-2.0f * (float)pr / (float)D) * 9.210340371976184f);
    float ang = (float)(t + 1) * theta;
    float s = sinf(ang);
    float c = cosf(ang);
    u16* p = Z + (size_t)row * stride + (pr << 1);
    float x1 = bf2f(p[0]);
    float x2 = bf2f(p[1]);
    p[0] = f2bf(x1 * c - x2 * s);
    p[1] = f2bf(x2 * c + x1 * s);
}

// ---------------------------------------------------------------------------
// MFMA flash attention, transposed (S^T) formulation.
//  S^T = K Q^T : A=K (LDS), B=Q (regs; A/B operand layouts coincide)
//  -> lane owns query col=ln: softmax in-register + 2 shfl_xor per reduction
//  P stored [query][key] (8B packs) -> read as B-operand of O^T = V^T P
//  O^T C-layout: col=query=ln -> alpha & 1/l per-lane scalars.
// Load balance: qtile flipped for b=1 so paired blocks sum to constant work.
// ---------------------------------------------------------------------------
#define KROW  136   // 128 + 8 pad
#define VROW  72    // 64 + 8
#define PROW  72    // 64 + 8

__global__ __launch_bounds__(256)
void attn_mfma(const u16* __restrict__ qh,
               const u16* __restrict__ qR, int qRstride,
               const u16* __restrict__ kv,
               const u16* __restrict__ kR, int kRstride,
               u16* __restrict__ out)
{
    __shared__ __align__(16) u16 Ks[64 * KROW];       // [key][d]
    __shared__ __align__(16) u16 Vt[64 * VROW];       // [dv][key]
    __shared__ __align__(16) u16 Ps[4 * 32 * PROW];   // per-wave [query][key]

    const int tid  = threadIdx.x;
    const int lane = tid & 63;
    const int ln   = lane & 15;
    const int quad = lane >> 4;
    const int wv   = tid >> 6;
    const int bh   = blockIdx.y;
    const int b    = bh >> 4;
    const int h    = bh & 15;
    const int bT   = b * T_;
    const int qt   = b ? (15 - blockIdx.x) : blockIdx.x;   // balance flip
    const int q0   = qt << 7;
    const int wq0  = q0 + wv * 32;
    const int wq1  = wq0 + 31;
    const float scale = 0.08838834764831845f;

    // Q fragments (B-operand): lane holds query n=ln, k=quad*8+j
    short8 aq[2][4];
    #pragma unroll
    for (int ni = 0; ni < 2; ++ni) {
        const size_t row = (size_t)(bT + wq0 + ni * 16 + ln);
        #pragma unroll
        for (int kk = 0; kk < 4; ++kk) {
            const int col = kk * 32 + quad * 8;
            const u16* src = (kk < 2)
                ? (qh + row * C_ + h * 64 + col)
                : (qR + row * qRstride + h * 64 + (col - 64));
            aq[ni][kk] = *(const short8*)src;
        }
    }

    f32x4 O[2][4];            // [ni][mt] : O^T[dv=mt*16+quad*4+r][query=ln]
    float m_run[2], l_run[2];
    #pragma unroll
    for (int ni = 0; ni < 2; ++ni) {
        m_run[ni] = -1e30f;
        l_run[ni] = 0.f;
        #pragma unroll
        for (int mt = 0; mt < 4; ++mt) O[ni][mt] = (f32x4){0.f, 0.f, 0.f, 0.f};
    }

    const int ntiles = 2 * qt + 2;

    for (int kt = 0; kt < ntiles; ++kt) {
        const int k0    = kt << 6;
        const int kbase = bT + k0;

        // ---- stage K tile [64 keys x 128 d] ----
        #pragma unroll
        for (int it = 0; it < 4; ++it) {
            int flat = tid + (it << 8);
            int j    = flat >> 4;
            int c8   = (flat & 15) << 3;
            const u16* src = (c8 < 64)
                ? (kv + (size_t)(kbase + j) * (2 * C_) + h * 64 + c8)
                : (kR + (size_t)(kbase + j) * kRstride + (c8 - 64));
            *(short8*)(&Ks[j * KROW + c8]) = *(const short8*)src;
        }
        // ---- stage V tile transposed [dv][key] ----
        #pragma unroll
        for (int it = 0; it < 2; ++it) {
            int flat = tid + (it << 8);
            int j    = flat >> 3;
            int c8   = (flat & 7) << 3;
            short8 v = *(const short8*)(kv + (size_t)(kbase + j) * (2 * C_) + C_ + h * 64 + c8);
            #pragma unroll
            for (int e = 0; e < 8; ++e)
                Vt[(c8 + e) * VROW + j] = v[e];
        }
        __syncthreads();

        if (k0 <= wq1) {
            // ---- S^T = K Q^T ----
            f32x4 S[2][4];    // [ni][mi]: D[key=mi*16+quad*4+r][query=ln]
            #pragma unroll
            for (int ni = 0; ni < 2; ++ni)
                #pragma unroll
                for (int mi = 0; mi < 4; ++mi)
                    S[ni][mi] = (f32x4){0.f, 0.f, 0.f, 0.f};

            #pragma unroll
            for (int kk = 0; kk < 4; ++kk) {
                #pragma unroll
                for (int mi = 0; mi < 4; ++mi) {
                    short8 ak = *(const short8*)(&Ks[(mi * 16 + ln) * KROW + kk * 32 + quad * 8]);
                    S[0][mi] = __builtin_amdgcn_mfma_f32_16x16x32_bf16(ak, aq[0][kk], S[0][mi], 0, 0, 0);
                    S[1][mi] = __builtin_amdgcn_mfma_f32_16x16x32_bf16(ak, aq[1][kk], S[1][mi], 0, 0, 0);
                }
            }

            const bool full = (k0 + 63) <= wq0;

            // ---- per-lane softmax over 16 regs + 2-shfl cross-quad ----
            #pragma unroll
            for (int ni = 0; ni < 2; ++ni) {
                const int qg = wq0 + ni * 16 + ln;
                float sv[16];
                float mloc = -1e30f;
                #pragma unroll
                for (int mi = 0; mi < 4; ++mi)
                    #pragma unroll
                    for (int r = 0; r < 4; ++r) {
                        float s = S[ni][mi][r] * scale;
                        if (!full) {
                            int key = k0 + mi * 16 + quad * 4 + r;
                            if (key > qg) s = -1e30f;
                        }
                        sv[mi * 4 + r] = s;
                        mloc = fmaxf(mloc, s);
                    }
                mloc = fmaxf(mloc, __shfl_xor(mloc, 16));
                mloc = fmaxf(mloc, __shfl_xor(mloc, 32));
                const float mold  = m_run[ni];
                const float mnew  = fmaxf(mold, mloc);
                const float alpha = __expf(mold - mnew);
                m_run[ni] = mnew;

                float lsum = 0.f;
                #pragma unroll
                for (int mi = 0; mi < 4; ++mi) {
                    float p0 = __expf(sv[mi * 4 + 0] - mnew);
                    float p1 = __expf(sv[mi * 4 + 1] - mnew);
                    float p2 = __expf(sv[mi * 4 + 2] - mnew);
                    float p3 = __expf(sv[mi * 4 + 3] - mnew);
                    lsum += (p0 + p1) + (p2 + p3);
                    short4v pk;
                    pk[0] = f2bf(p0); pk[1] = f2bf(p1);
                    pk[2] = f2bf(p2); pk[3] = f2bf(p3);
                    *(short4v*)(&Ps[(wv * 32 + ni * 16 + ln) * PROW + mi * 16 + quad * 4]) = pk;
                }
                lsum += __shfl_xor(lsum, 16);
                lsum += __shfl_xor(lsum, 32);
                l_run[ni] = l_run[ni] * alpha + lsum;

                #pragma unroll
                for (int mt = 0; mt < 4; ++mt) {
                    O[ni][mt][0] *= alpha;
                    O[ni][mt][1] *= alpha;
                    O[ni][mt][2] *= alpha;
                    O[ni][mt][3] *= alpha;
                }
            }

            asm volatile("s_waitcnt lgkmcnt(0)" ::: "memory");

            // ---- O^T += V^T P ----
            #pragma unroll
            for (int c = 0; c < 2; ++c) {
                short8 pb0 = *(const short8*)(&Ps[(wv * 32 +  0 + ln) * PROW + c * 32 + quad * 8]);
                short8 pb1 = *(const short8*)(&Ps[(wv * 32 + 16 + ln) * PROW + c * 32 + quad * 8]);
                #pragma unroll
                for (int mt = 0; mt < 4; ++mt) {
                    short8 av = *(const short8*)(&Vt[(mt * 16 + ln) * VROW + c * 32 + quad * 8]);
                    O[0][mt] = __builtin_amdgcn_mfma_f32_16x16x32_bf16(av, pb0, O[0][mt], 0, 0, 0);
                    O[1][mt] = __builtin_amdgcn_mfma_f32_16x16x32_bf16(av, pb1, O[1][mt], 0, 0, 0);
                }
            }
        }
        __syncthreads();
    }

    // ---- epilogue: out[query][h*64 + dv] ----
    #pragma unroll
    for (int ni = 0; ni < 2; ++ni) {
        const float inv = 1.0f / l_run[ni];
        const size_t row = (size_t)(bT + wq0 + ni * 16 + ln);
        #pragma unroll
        for (int mt = 0; mt < 4; ++mt) {
            short4v o;
            o[0] = f2bf(O[ni][mt][0] * inv);
            o[1] = f2bf(O[ni][mt][1] * inv);
            o[2] = f2bf(O[ni][mt][2] * inv);
            o[3] = f2bf(O[ni][mt][3] * inv);
            *(short4v*)(out + row * C_ + h * 64 + mt * 16 + quad * 4) = o;
        }
    }
}

// ---------------------------------------------------------------------------
extern "C" void kernel_launch(void* const* d_in, const int* in_sizes, int n_in,
                              void* d_out, int out_size, void* d_ws, size_t ws_size,
                              hipStream_t stream)
{
    const float* x   = (const float*)d_in[0];
    const float* w1  = (const float*)d_in[1];
    const float* b1  = (const float*)d_in[2];
    const float* wkr = (const float*)d_in[3];
    const float* bkr = (const float*)d_in[4];
    const float* wqr = (const float*)d_in[5];
    const float* bqr = (const float*)d_in[6];
    const float* wkv = (const float*)d_in[7];
    const float* bkv = (const float*)d_in[8];
    const float* wq  = (const float*)d_in[9];
    const float* bq  = (const float*)d_in[10];
    const float* wo  = (const float*)d_in[11];
    const float* bo  = (const float*)d_in[12];
    float* out = (float*)d_out;

    // workspace (u16 units); buf0/buf1 aliased across phases
    u16* ws    = (u16*)d_ws;
    u16* buf0  = ws;                    // xb, later qb     (4096*1024)
    u16* buf1  = buf0 + 4194304;        // hb, later attnb  (4096*1024)
    u16* Zqk   = buf1 + 4194304;        // 4096*1152 (qRt | kRt | pad)
    u16* kvbb  = Zqk  + 4718592;        // 4096*2048
    u16* w1t   = kvbb + 8388608;        // 1024*1024
    u16* wqkt  = w1t  + 1048576;        // 1152*1024
    u16* wkvt  = wqkt + 1179648;        // 2048*512
    u16* wqt   = wkvt + 1048576;        // 1024*512
    u16* wot   = wqt  + 524288;         // 1024*1024
    float* bqk = (float*)(wot + 1048576); // 1152 floats

    u16* xb    = buf0;
    u16* qb    = buf0;
    u16* hb    = buf1;
    u16* attnb = buf1;

    dim3 blk(256);

    // prep
    cvt_f2b<<<4096, blk, 0, stream>>>(x, xb, M_ * C_ / 4);
    transpose_cvt<<<dim3(32, 32), blk, 0, stream>>>(w1,  w1t,  1024, 1024);
    transpose_cvt<<<dim3(32, 32), blk, 0, stream>>>(wqr, wqkt, 1024, 1024);
    transpose_cvt<<<dim3( 2, 32), blk, 0, stream>>>(wkr, wqkt + 1024 * 1024, 1024, 64);
    transpose_cvt<<<dim3(64, 16), blk, 0, stream>>>(wkv, wkvt,  512, 2048);
    transpose_cvt<<<dim3(32, 16), blk, 0, stream>>>(wq,  wqt,   512, 1024);
    transpose_cvt<<<dim3(32, 32), blk, 0, stream>>>(wo,  wot,  1024, 1024);
    concat_bias<<<5, blk, 0, stream>>>(bqr, bkr, bqk);

    // h = x @ w1 + b1                       [4096,1024] bf16
    gemm_mfma<2, 2, false><<<dim3(8, 32), blk, 0, stream>>>(xb, 1024, w1t, b1, hb, 1024, 1024);
    // Zqk = h @ [wqr|wkr|pad] + [bqr|bkr|0] [4096,1152] bf16 (fused qRt+kRt)
    gemm_mfma<2, 2, false><<<dim3(9, 32), blk, 0, stream>>>(hb, 1024, wqkt, bqk, Zqk, 1152, 1024);
    // rope on qRt (cols 0..1023) and kRt (cols 1024..1087) views of Zqk
    rope_bf<<<(M_ * 512 + 255) / 256, blk, 0, stream>>>(Zqk, 1152, 1024, 9, M_ * 512);
    rope_bf<<<(M_ * 32 + 255) / 256, blk, 0, stream>>>(Zqk + 1024, 1152, 64, 5, M_ * 32);
    // kv = h[:, :512] @ wkv + bkv           [4096,2048]
    gemm_mfma<2, 2, false><<<dim3(16, 32), blk, 0, stream>>>(hb, 1024, wkvt, bkv, kvbb, 2048, 512);
    // q = h[:, 512:] @ wq + bq              [4096,1024]
    gemm_mfma<2, 2, false><<<dim3(8, 32), blk, 0, stream>>>(hb + 512, 1024, wqt, bq, qb, 1024, 512);
    // attention
    attn_mfma<<<dim3(16, 32), blk, 0, stream>>>(qb, Zqk, 1152, kvbb, Zqk + 1024, 1152, attnb);
    // out = attn @ wo + bo                  [4096,1024] fp32
    gemm_mfma<2, 2, true><<<dim3(8, 32), blk, 0, stream>>>(attnb, 1024, wot, bo, out, 1024, 1024);
}

// Round 6
// 288.671 us; speedup vs baseline: 8.0082x; 1.1654x over previous
//
#include <hip/hip_runtime.h>
#include <math.h>
#include <stdint.h>

#define B_   2
#define T_   2048
#define C_   1024
#define NH_  16
#define LAT_ 512
#define DHR_ 64
#define M_   (B_*T_)   // 4096

typedef unsigned short u16;
typedef short short8 __attribute__((ext_vector_type(8)));
typedef short short4v __attribute__((ext_vector_type(4)));
typedef float f32x4 __attribute__((ext_vector_type(4)));

__device__ __forceinline__ u16 f2bf(float f) {          // RNE
    union { float f; unsigned u; } x; x.f = f;
    unsigned r = x.u + 0x7fffu + ((x.u >> 16) & 1u);
    return (u16)(r >> 16);
}
__device__ __forceinline__ u16 f2bf_fast(float f) {     // round-nearest (P in [0,1])
    union { float f; unsigned u; } x; x.f = f;
    return (u16)((x.u + 0x8000u) >> 16);
}
__device__ __forceinline__ float bf2f(u16 v) {
    union { unsigned u; float f; } x; x.u = ((unsigned)v) << 16;
    return x.f;
}

// async global->LDS, 16B per lane (m97)
__device__ __forceinline__ void gl_lds16(const void* g, void* l) {
    auto* gp = reinterpret_cast<const __attribute__((address_space(1))) unsigned*>(
        reinterpret_cast<uintptr_t>(g));
    auto* lp = reinterpret_cast<__attribute__((address_space(3))) unsigned*>(
        reinterpret_cast<uintptr_t>(l));
    __builtin_amdgcn_global_load_lds(gp, lp, 16, 0, 0);
}

// ---------------------------------------------------------------------------
__global__ void cvt_f2b(const float* __restrict__ X, u16* __restrict__ Xb, int n4)
{
    int i = blockIdx.x * 256 + threadIdx.x;
    if (i >= n4) return;
    float4 v = ((const float4*)X)[i];
    short4v s;
    s[0] = f2bf(v.x); s[1] = f2bf(v.y); s[2] = f2bf(v.z); s[3] = f2bf(v.w);
    ((short4v*)Xb)[i] = s;
}

// ---------------------------------------------------------------------------
// Merged weight prep: all 6 transposes (fp32 [K,N] -> bf16 [N,K]) + bias concat
// ---------------------------------------------------------------------------
__device__ __forceinline__ void tr_tile(const float* __restrict__ W,
                                        u16* __restrict__ Wt,
                                        int K, int N, int bx, int by, int tid,
                                        float (*t)[33])
{
    const int tx = tid & 31;
    const int ty = tid >> 5;
    const int n0 = bx << 5;
    const int k0 = by << 5;
    #pragma unroll
    for (int r = 0; r < 4; ++r) {
        int row = ty + (r << 3);
        t[row][tx] = W[(size_t)(k0 + row) * N + n0 + tx];
    }
    __syncthreads();
    #pragma unroll
    for (int r = 0; r < 4; ++r) {
        int row = ty + (r << 3);
        Wt[(size_t)(n0 + row) * K + k0 + tx] = f2bf(t[tx][row]);
    }
}

__global__ __launch_bounds__(256)
void prep_weights(const float* __restrict__ w1,  const float* __restrict__ wqr,
                  const float* __restrict__ wkr, const float* __restrict__ wkv,
                  const float* __restrict__ wq,  const float* __restrict__ wo,
                  u16* __restrict__ w1t,  u16* __restrict__ wqkt,
                  u16* __restrict__ wkvt, u16* __restrict__ wqt,
                  u16* __restrict__ wot,
                  const float* __restrict__ bqr, const float* __restrict__ bkr,
                  float* __restrict__ bqk)
{
    __shared__ float t[32][33];
    int id = blockIdx.x;
    const int tid = threadIdx.x;
    if (id < 1024)      { tr_tile(w1,  w1t,  1024, 1024, id % 32, id / 32, tid, t); return; }
    id -= 1024;
    if (id < 1024)      { tr_tile(wqr, wqkt, 1024, 1024, id % 32, id / 32, tid, t); return; }
    id -= 1024;
    if (id < 64)        { tr_tile(wkr, wqkt + 1024 * 1024, 1024, 64, id % 2, id / 2, tid, t); return; }
    id -= 64;
    if (id < 1024)      { tr_tile(wkv, wkvt, 512, 2048, id % 64, id / 64, tid, t); return; }
    id -= 1024;
    if (id < 512)       { tr_tile(wq,  wqt,  512, 1024, id % 32, id / 32, tid, t); return; }
    id -= 512;
    if (id < 1024)      { tr_tile(wo,  wot,  1024, 1024, id % 32, id / 32, tid, t); return; }
    // last block: bias concat
    for (int i = tid; i < 1152; i += 256) {
        float v;
        if (i < 1024)      v = bqr[i];
        else if (i < 1088) v = bkr[i - 1024];
        else               v = 0.f;
        bqk[i] = v;
    }
}

// ---------------------------------------------------------------------------
// 128x128 bf16 MFMA GEMM body (dbuf LDS, global_load_lds staging, BK=32)
// ---------------------------------------------------------------------------
__device__ __forceinline__ void gemm128_body(
    u16* __restrict__ AsB, u16* __restrict__ BsB,   // 2*4096 elems each
    const u16* __restrict__ A, int lda,
    const u16* __restrict__ Bt, const float* __restrict__ bias,
    void* __restrict__ Out, bool outf32, int N, int K, int m0, int n0, int tid)
{
    const int lane = tid & 63;
    const int ln   = lane & 15;
    const int quad = lane >> 4;
    const int wv   = tid >> 6;
    const int wm   = (wv & 1) << 6;
    const int wn   = (wv >> 1) << 6;

    f32x4 acc[4][4];
    #pragma unroll
    for (int i = 0; i < 4; ++i)
        #pragma unroll
        for (int j = 0; j < 4; ++j) acc[i][j] = (f32x4){0.f, 0.f, 0.f, 0.f};

    auto stage = [&](int bufi, int k0) {
        u16* As = AsB + bufi * 4096;
        u16* Bs = BsB + bufi * 4096;
        #pragma unroll
        for (int it = 0; it < 2; ++it) {
            int flat = it * 256 + tid;
            int row  = flat >> 2;
            int ko   = (flat & 3) << 3;
            gl_lds16(A + (size_t)(m0 + row) * lda + k0 + ko, &As[flat * 8]);
        }
        #pragma unroll
        for (int it = 0; it < 2; ++it) {
            int flat = it * 256 + tid;
            int row  = flat >> 2;
            int ko   = (flat & 3) << 3;
            gl_lds16(Bt + (size_t)(n0 + row) * K + k0 + ko, &Bs[flat * 8]);
        }
    };

    stage(0, 0);
    __syncthreads();

    int buf = 0;
    for (int k0 = 0; k0 < K; k0 += 32) {
        if (k0 + 32 < K) stage(buf ^ 1, k0 + 32);

        u16* As = AsB + buf * 4096;
        u16* Bs = BsB + buf * 4096;
        short8 af[4], bfv[4];
        #pragma unroll
        for (int mi = 0; mi < 4; ++mi)
            af[mi] = *(const short8*)(&As[(wm + mi * 16 + ln) * 32 + quad * 8]);
        #pragma unroll
        for (int ni = 0; ni < 4; ++ni)
            bfv[ni] = *(const short8*)(&Bs[(wn + ni * 16 + ln) * 32 + quad * 8]);
        #pragma unroll
        for (int mi = 0; mi < 4; ++mi)
            #pragma unroll
            for (int ni = 0; ni < 4; ++ni)
                acc[mi][ni] = __builtin_amdgcn_mfma_f32_16x16x32_bf16(af[mi], bfv[ni], acc[mi][ni], 0, 0, 0);

        __syncthreads();
        buf ^= 1;
    }

    float bb[4];
    #pragma unroll
    for (int ni = 0; ni < 4; ++ni) bb[ni] = bias[n0 + wn + ni * 16 + ln];

    #pragma unroll
    for (int mi = 0; mi < 4; ++mi) {
        #pragma unroll
        for (int r = 0; r < 4; ++r) {
            const size_t row = (size_t)(m0 + wm + mi * 16 + quad * 4 + r);
            #pragma unroll
            for (int ni = 0; ni < 4; ++ni) {
                float v = acc[mi][ni][r] + bb[ni];
                const size_t idx = row * N + n0 + wn + ni * 16 + ln;
                if (outf32) ((float*)Out)[idx] = v;
                else        ((u16*)Out)[idx]  = f2bf(v);
            }
        }
    }
}

template<bool OUTF32>
__global__ __launch_bounds__(256)
void gemm_mfma(const u16* __restrict__ A, int lda,
               const u16* __restrict__ Bt,
               const float* __restrict__ bias,
               void* __restrict__ Out, int N, int K)
{
    __shared__ __align__(16) u16 As[2 * 4096];
    __shared__ __align__(16) u16 Bs[2 * 4096];
    gemm128_body(As, Bs, A, lda, Bt, bias, Out, OUTF32,
                 N, K, blockIdx.y * 128, blockIdx.x * 128, threadIdx.x);
}

// merged qk + kv + q GEMMs (one dispatch, 1056 blocks -> 4/CU)
__global__ __launch_bounds__(256)
void gemm3(const u16* __restrict__ hb,
           const u16* __restrict__ wqkt, const float* __restrict__ bqk, u16* __restrict__ Zqk,
           const u16* __restrict__ wkvt, const float* __restrict__ bkv, u16* __restrict__ kvbb,
           const u16* __restrict__ wqt,  const float* __restrict__ bq,  u16* __restrict__ qb)
{
    __shared__ __align__(16) u16 As[2 * 4096];
    __shared__ __align__(16) u16 Bs[2 * 4096];
    int id = blockIdx.x;
    const u16* A; const u16* Bt; const float* bias; u16* Out; int N, K, bx, by;
    if (id < 288)      { A = hb;       Bt = wqkt; bias = bqk; Out = Zqk;  N = 1152; K = 1024; bx = id % 9;  by = id / 9; }
    else if (id < 800) { id -= 288; A = hb;       Bt = wkvt; bias = bkv; Out = kvbb; N = 2048; K = 512;  bx = id % 16; by = id / 16; }
    else               { id -= 800; A = hb + 512; Bt = wqt;  bias = bq;  Out = qb;   N = 1024; K = 512;  bx = id % 8;  by = id / 8; }
    gemm128_body(As, Bs, A, 1024, Bt, bias, Out, false, N, K, by * 128, bx * 128, threadIdx.x);
}

// ---------------------------------------------------------------------------
// Merged RoPE: qRt part (D=1024, 512 pairs/row) + kRt part (D=64, 32 pairs/row)
// Both live in Zqk with row stride 1152.
// ---------------------------------------------------------------------------
__global__ void rope_bf(u16* __restrict__ Zqk)
{
    int idx = blockIdx.x * 256 + threadIdx.x;
    u16* p;
    int t;
    float e;
    if (idx < M_ * 512) {
        int row = idx >> 9, pr = idx & 511;
        e = (-2.0f * (float)pr / 1024.0f) * 9.210340371976184f;
        p = Zqk + (size_t)row * 1152 + (pr << 1);
        t = row & (T_ - 1);
    } else {
        int r = idx - M_ * 512;
        if (r >= M_ * 32) return;
        int row = r >> 5, pr = r & 31;
        e = (-2.0f * (float)pr / 64.0f) * 9.210340371976184f;
        p = Zqk + 1024 + (size_t)row * 1152 + (pr << 1);
        t = row & (T_ - 1);
    }
    float theta = expf(e);
    float ang = (float)(t + 1) * theta;
    float s = sinf(ang), c = cosf(ang);
    float x1 = bf2f(p[0]);
    float x2 = bf2f(p[1]);
    p[0] = f2bf(x1 * c - x2 * s);
    p[1] = f2bf(x2 * c + x1 * s);
}

// ---------------------------------------------------------------------------
// MFMA flash attention v3: paired query tiles sharing staged K/V,
// 2-deep prefetch pipeline, dbuf LDS, ONE barrier per K-tile.
// Grid (8, 32): 256 uniform blocks (1/CU). Block handles qtA=x, qtB=15-x.
// ---------------------------------------------------------------------------
#define KROW  136   // 128 + 8 pad
#define VROW  72    // 64 + 8
#define PROW  72    // 64 + 8

__global__ __launch_bounds__(256, 1)
void attn_mfma(const u16* __restrict__ qh,
               const u16* __restrict__ qR, int qRstride,
               const u16* __restrict__ kv,
               const u16* __restrict__ kR, int kRstride,
               u16* __restrict__ out)
{
    __shared__ __align__(16) u16 Ks[2][64 * KROW];   // [key][d]
    __shared__ __align__(16) u16 Vt[2][64 * VROW];   // [dv][key]
    __shared__ __align__(16) u16 Ps[4 * 32 * PROW];  // per-wave [query][key]

    const int tid  = threadIdx.x;
    const int lane = tid & 63;
    const int ln   = lane & 15;
    const int quad = lane >> 4;
    const int wv   = tid >> 6;
    const int bh   = blockIdx.y;
    const int b    = bh >> 4;
    const int h    = bh & 15;
    const int bT   = b * T_;
    const int qtA  = blockIdx.x;        // 0..7
    const int qtB  = 15 - qtA;          // 8..15
    const float scale2 = 0.08838834764831845f * 1.4426950408889634f;  // /sqrt(128)*log2e

    const int wq[2] = { qtA * 128 + wv * 32, qtB * 128 + wv * 32 };

    // Q fragments (B-operand), both jobs
    short8 aq[2][2][4];
    #pragma unroll
    for (int job = 0; job < 2; ++job)
        #pragma unroll
        for (int ni = 0; ni < 2; ++ni) {
            const size_t row = (size_t)(bT + wq[job] + ni * 16 + ln);
            #pragma unroll
            for (int kk = 0; kk < 4; ++kk) {
                const int col = kk * 32 + quad * 8;
                const u16* src = (kk < 2)
                    ? (qh + row * C_ + h * 64 + col)
                    : (qR + row * qRstride + h * 64 + (col - 64));
                aq[job][ni][kk] = *(const short8*)src;
            }
        }

    f32x4 O[2][2][4];
    float m_run[2][2], l_run[2][2];
    #pragma unroll
    for (int job = 0; job < 2; ++job)
        #pragma unroll
        for (int ni = 0; ni < 2; ++ni) {
            m_run[job][ni] = -1e30f;
            l_run[job][ni] = 0.f;
            #pragma unroll
            for (int mt = 0; mt < 4; ++mt) O[job][ni][mt] = (f32x4){0.f, 0.f, 0.f, 0.f};
        }

    const int ntiles = 2 * qtB + 2;

    // prefetch registers (one tile)
    short8 kreg[4];
    u16    vreg[2][8];

    auto prefetch = [&](int kt) {
        const int kbase = bT + (kt << 6);
        #pragma unroll
        for (int it = 0; it < 4; ++it) {
            int flat = tid + (it << 8);
            int j    = flat >> 4;
            int c8   = (flat & 15) << 3;
            const u16* src = (c8 < 64)
                ? (kv + (size_t)(kbase + j) * (2 * C_) + h * 64 + c8)
                : (kR + (size_t)(kbase + j) * kRstride + (c8 - 64));
            kreg[it] = *(const short8*)src;
        }
        #pragma unroll
        for (int it = 0; it < 2; ++it) {
            int flat = tid + (it << 8);        // 0..511
            int dv   = flat & 63;
            int kg   = flat >> 6;              // 0..7
            const u16* vs = kv + (size_t)(kbase + kg * 8) * (2 * C_) + C_ + h * 64 + dv;
            #pragma unroll
            for (int j = 0; j < 8; ++j) vreg[it][j] = vs[(size_t)j * (2 * C_)];
        }
    };
    auto lds_write = [&](int bufi) {
        #pragma unroll
        for (int it = 0; it < 4; ++it) {
            int flat = tid + (it << 8);
            int j    = flat >> 4;
            int c8   = (flat & 15) << 3;
            *(short8*)(&Ks[bufi][j * KROW + c8]) = kreg[it];
        }
        #pragma unroll
        for (int it = 0; it < 2; ++it) {
            int flat = tid + (it << 8);
            int dv   = flat & 63;
            int kg   = flat >> 6;
            short8 vv;
            #pragma unroll
            for (int j = 0; j < 8; ++j) vv[j] = (short)vreg[it][j];
            *(short8*)(&Vt[bufi][dv * VROW + kg * 8]) = vv;
        }
    };

    prefetch(0);
    lds_write(0);
    prefetch(1);
    __syncthreads();

    for (int kt = 0; kt < ntiles; ++kt) {
        const int cur = kt & 1;
        if (kt + 1 < ntiles) lds_write(cur ^ 1);   // regs hold tile kt+1
        if (kt + 2 < ntiles) prefetch(kt + 2);     // 2-deep pipeline

        const int k0 = kt << 6;

        #pragma unroll
        for (int job = 0; job < 2; ++job) {
            const int wq0 = wq[job];
            if (k0 > wq0 + 31) continue;           // wave-uniform per job

            // ---- S^T = K Q^T ----
            f32x4 S[2][4];
            #pragma unroll
            for (int ni = 0; ni < 2; ++ni)
                #pragma unroll
                for (int mi = 0; mi < 4; ++mi)
                    S[ni][mi] = (f32x4){0.f, 0.f, 0.f, 0.f};

            #pragma unroll
            for (int kk = 0; kk < 4; ++kk) {
                #pragma unroll
                for (int mi = 0; mi < 4; ++mi) {
                    short8 ak = *(const short8*)(&Ks[cur][(mi * 16 + ln) * KROW + kk * 32 + quad * 8]);
                    S[0][mi] = __builtin_amdgcn_mfma_f32_16x16x32_bf16(ak, aq[job][0][kk], S[0][mi], 0, 0, 0);
                    S[1][mi] = __builtin_amdgcn_mfma_f32_16x16x32_bf16(ak, aq[job][1][kk], S[1][mi], 0, 0, 0);
                }
            }

            const bool full = (k0 + 63) <= wq0;

            // ---- per-lane online softmax (exp2 domain) ----
            #pragma unroll
            for (int ni = 0; ni < 2; ++ni) {
                const int qg = wq0 + ni * 16 + ln;
                float sv[16];
                float mloc = -1e30f;
                #pragma unroll
                for (int mi = 0; mi < 4; ++mi)
                    #pragma unroll
                    for (int r = 0; r < 4; ++r) {
                        float s = S[ni][mi][r] * scale2;
                        if (!full) {
                            int key = k0 + mi * 16 + quad * 4 + r;
                            if (key > qg) s = -1e30f;
                        }
                        sv[mi * 4 + r] = s;
                        mloc = fmaxf(mloc, s);
                    }
                mloc = fmaxf(mloc, __shfl_xor(mloc, 16));
                mloc = fmaxf(mloc, __shfl_xor(mloc, 32));
                const float mold  = m_run[job][ni];
                const float mnew  = fmaxf(mold, mloc);
                const float alpha = exp2f(mold - mnew);
                m_run[job][ni] = mnew;

                float lsum = 0.f;
                #pragma unroll
                for (int mi = 0; mi < 4; ++mi) {
                    float p0 = exp2f(sv[mi * 4 + 0] - mnew);
                    float p1 = exp2f(sv[mi * 4 + 1] - mnew);
                    float p2 = exp2f(sv[mi * 4 + 2] - mnew);
                    float p3 = exp2f(sv[mi * 4 + 3] - mnew);
                    lsum += (p0 + p1) + (p2 + p3);
                    short4v pk;
                    pk[0] = (short)f2bf_fast(p0); pk[1] = (short)f2bf_fast(p1);
                    pk[2] = (short)f2bf_fast(p2); pk[3] = (short)f2bf_fast(p3);
                    *(short4v*)(&Ps[(wv * 32 + ni * 16 + ln) * PROW + mi * 16 + quad * 4]) = pk;
                }
                lsum += __shfl_xor(lsum, 16);
                lsum += __shfl_xor(lsum, 32);
                l_run[job][ni] = l_run[job][ni] * alpha + lsum;

                #pragma unroll
                for (int mt = 0; mt < 4; ++mt) {
                    O[job][ni][mt][0] *= alpha;
                    O[job][ni][mt][1] *= alpha;
                    O[job][ni][mt][2] *= alpha;
                    O[job][ni][mt][3] *= alpha;
                }
            }

            asm volatile("s_waitcnt lgkmcnt(0)" ::: "memory");

            // ---- O^T += V^T P ----
            #pragma unroll
            for (int c = 0; c < 2; ++c) {
                short8 pb0 = *(const short8*)(&Ps[(wv * 32 +  0 + ln) * PROW + c * 32 + quad * 8]);
                short8 pb1 = *(const short8*)(&Ps[(wv * 32 + 16 + ln) * PROW + c * 32 + quad * 8]);
                #pragma unroll
                for (int mt = 0; mt < 4; ++mt) {
                    short8 av = *(const short8*)(&Vt[cur][(mt * 16 + ln) * VROW + c * 32 + quad * 8]);
                    O[job][0][mt] = __builtin_amdgcn_mfma_f32_16x16x32_bf16(av, pb0, O[job][0][mt], 0, 0, 0);
                    O[job][1][mt] = __builtin_amdgcn_mfma_f32_16x16x32_bf16(av, pb1, O[job][1][mt], 0, 0, 0);
                }
            }
        }
        __syncthreads();
    }

    // ---- epilogue ----
    #pragma unroll
    for (int job = 0; job < 2; ++job)
        #pragma unroll
        for (int ni = 0; ni < 2; ++ni) {
            const float inv = 1.0f / l_run[job][ni];
            const size_t row = (size_t)(bT + wq[job] + ni * 16 + ln);
            #pragma unroll
            for (int mt = 0; mt < 4; ++mt) {
                short4v o;
                o[0] = (short)f2bf(O[job][ni][mt][0] * inv);
                o[1] = (short)f2bf(O[job][ni][mt][1] * inv);
                o[2] = (short)f2bf(O[job][ni][mt][2] * inv);
                o[3] = (short)f2bf(O[job][ni][mt][3] * inv);
                *(short4v*)(out + row * C_ + h * 64 + mt * 16 + quad * 4) = o;
            }
        }
}

// ---------------------------------------------------------------------------
extern "C" void kernel_launch(void* const* d_in, const int* in_sizes, int n_in,
                              void* d_out, int out_size, void* d_ws, size_t ws_size,
                              hipStream_t stream)
{
    const float* x   = (const float*)d_in[0];
    const float* w1  = (const float*)d_in[1];
    const float* b1  = (const float*)d_in[2];
    const float* wkr = (const float*)d_in[3];
    const float* bkr = (const float*)d_in[4];
    const float* wqr = (const float*)d_in[5];
    const float* bqr = (const float*)d_in[6];
    const float* wkv = (const float*)d_in[7];
    const float* bkv = (const float*)d_in[8];
    const float* wq  = (const float*)d_in[9];
    const float* bq  = (const float*)d_in[10];
    const float* wo  = (const float*)d_in[11];
    const float* bo  = (const float*)d_in[12];
    float* out = (float*)d_out;

    // workspace (u16 units); buf0/buf1 aliased across phases
    u16* ws    = (u16*)d_ws;
    u16* buf0  = ws;                    // xb, later qb     (4096*1024)
    u16* buf1  = buf0 + 4194304;        // hb, later attnb  (4096*1024)
    u16* Zqk   = buf1 + 4194304;        // 4096*1152 (qRt | kRt | pad)
    u16* kvbb  = Zqk  + 4718592;        // 4096*2048
    u16* w1t   = kvbb + 8388608;        // 1024*1024
    u16* wqkt  = w1t  + 1048576;        // 1152*1024
    u16* wkvt  = wqkt + 1179648;        // 2048*512
    u16* wqt   = wkvt + 1048576;        // 1024*512
    u16* wot   = wqt  + 524288;         // 1024*1024
    float* bqk = (float*)(wot + 1048576); // 1152 floats

    u16* xb    = buf0;
    u16* qb    = buf0;
    u16* hb    = buf1;
    u16* attnb = buf1;

    dim3 blk(256);

    cvt_f2b<<<4096, blk, 0, stream>>>(x, xb, M_ * C_ / 4);
    prep_weights<<<4673, blk, 0, stream>>>(w1, wqr, wkr, wkv, wq, wo,
                                           w1t, wqkt, wkvt, wqt, wot,
                                           bqr, bkr, bqk);

    // h = x @ w1 + b1                       [4096,1024] bf16
    gemm_mfma<false><<<dim3(8, 32), blk, 0, stream>>>(xb, 1024, w1t, b1, hb, 1024, 1024);
    // fused: Zqk / kv / q
    gemm3<<<1056, blk, 0, stream>>>(hb, wqkt, bqk, Zqk, wkvt, bkv, kvbb, wqt, bq, qb);
    // rope (merged qRt + kRt)
    rope_bf<<<(M_ * 544 + 255) / 256, blk, 0, stream>>>(Zqk);
    // attention
    attn_mfma<<<dim3(8, 32), blk, 0, stream>>>(qb, Zqk, 1152, kvbb, Zqk + 1024, 1152, attnb);
    // out = attn @ wo + bo                  [4096,1024] fp32
    gemm_mfma<true><<<dim3(8, 32), blk, 0, stream>>>(attnb, 1024, wot, bo, out, 1024, 1024);
}

// Round 7
// 251.295 us; speedup vs baseline: 9.1993x; 1.1487x over previous
//
#include <hip/hip_runtime.h>
#include <math.h>
#include <stdint.h>

#define B_   2
#define T_   2048
#define C_   1024
#define NH_  16
#define LAT_ 512
#define DHR_ 64
#define M_   (B_*T_)   // 4096

typedef unsigned short u16;
typedef short short8 __attribute__((ext_vector_type(8)));
typedef short short4v __attribute__((ext_vector_type(4)));
typedef float f32x4 __attribute__((ext_vector_type(4)));

#define SCALE2 0.12752455489626498f   // (1/sqrt(128)) * log2(e)

__device__ __forceinline__ u16 f2bf(float f) {          // RNE
    union { float f; unsigned u; } x; x.f = f;
    unsigned r = x.u + 0x7fffu + ((x.u >> 16) & 1u);
    return (u16)(r >> 16);
}
__device__ __forceinline__ u16 f2bf_fast(float f) {     // P in [0,1]
    union { float f; unsigned u; } x; x.f = f;
    return (u16)((x.u + 0x8000u) >> 16);
}
__device__ __forceinline__ float bf2f(u16 v) {
    union { unsigned u; float f; } x; x.u = ((unsigned)v) << 16;
    return x.f;
}

// async global->LDS, 16B per lane (m97)
__device__ __forceinline__ void gl_lds16(const void* g, void* l) {
    auto* gp = reinterpret_cast<const __attribute__((address_space(1))) unsigned*>(
        reinterpret_cast<uintptr_t>(g));
    auto* lp = reinterpret_cast<__attribute__((address_space(3))) unsigned*>(
        reinterpret_cast<uintptr_t>(l));
    __builtin_amdgcn_global_load_lds(gp, lp, 16, 0, 0);
}

// ---------------------------------------------------------------------------
// Merged prep: x f32->bf16 + all 6 weight transposes + bias concat
// ---------------------------------------------------------------------------
__device__ __forceinline__ void tr_tile(const float* __restrict__ W,
                                        u16* __restrict__ Wt,
                                        int K, int N, int bx, int by, int tid,
                                        float (*t)[33])
{
    const int tx = tid & 31;
    const int ty = tid >> 5;
    const int n0 = bx << 5;
    const int k0 = by << 5;
    #pragma unroll
    for (int r = 0; r < 4; ++r) {
        int row = ty + (r << 3);
        t[row][tx] = W[(size_t)(k0 + row) * N + n0 + tx];
    }
    __syncthreads();
    #pragma unroll
    for (int r = 0; r < 4; ++r) {
        int row = ty + (r << 3);
        Wt[(size_t)(n0 + row) * K + k0 + tx] = f2bf(t[tx][row]);
    }
}

__global__ __launch_bounds__(256)
void prep_all(const float* __restrict__ x, u16* __restrict__ xb,
              const float* __restrict__ w1,  const float* __restrict__ wqr,
              const float* __restrict__ wkr, const float* __restrict__ wkv,
              const float* __restrict__ wq,  const float* __restrict__ wo,
              u16* __restrict__ w1t,  u16* __restrict__ wqkt,
              u16* __restrict__ wkvt, u16* __restrict__ wqt,
              u16* __restrict__ wot,
              const float* __restrict__ bqr, const float* __restrict__ bkr,
              float* __restrict__ bqk)
{
    __shared__ float t[32][33];
    int id = blockIdx.x;
    const int tid = threadIdx.x;
    if (id < 4096) {     // cvt x (4M elems / 4 per thread)
        int i = id * 256 + tid;
        float4 v = ((const float4*)x)[i];
        short4v s;
        s[0] = f2bf(v.x); s[1] = f2bf(v.y); s[2] = f2bf(v.z); s[3] = f2bf(v.w);
        ((short4v*)xb)[i] = s;
        return;
    }
    id -= 4096;
    if (id < 1024)      { tr_tile(w1,  w1t,  1024, 1024, id % 32, id / 32, tid, t); return; }
    id -= 1024;
    if (id < 1024)      { tr_tile(wqr, wqkt, 1024, 1024, id % 32, id / 32, tid, t); return; }
    id -= 1024;
    if (id < 64)        { tr_tile(wkr, wqkt + 1024 * 1024, 1024, 64, id % 2, id / 2, tid, t); return; }
    id -= 64;
    if (id < 1024)      { tr_tile(wkv, wkvt, 512, 2048, id % 64, id / 64, tid, t); return; }
    id -= 1024;
    if (id < 512)       { tr_tile(wq,  wqt,  512, 1024, id % 32, id / 32, tid, t); return; }
    id -= 512;
    if (id < 1024)      { tr_tile(wo,  wot,  1024, 1024, id % 32, id / 32, tid, t); return; }
    for (int i = tid; i < 1152; i += 256) {
        float v;
        if (i < 1024)      v = bqr[i];
        else if (i < 1088) v = bkr[i - 1024];
        else               v = 0.f;
        bqk[i] = v;
    }
}

// ---------------------------------------------------------------------------
// bf16 MFMA GEMM body, BM x BN tile, BK=32, dbuf LDS, gl_lds16 staging.
// 4 waves in 2x2 grid; wave tile (BM/2) x (BN/2).
// ---------------------------------------------------------------------------
template<int BM, int BN>
__device__ __forceinline__ void gemm_body(
    u16* __restrict__ AsB, u16* __restrict__ BsB,
    const u16* __restrict__ A, int lda,
    const u16* __restrict__ Bt, const float* __restrict__ bias,
    void* __restrict__ Out, bool outf32, float oscale,
    int N, int K, int m0, int n0, int tid)
{
    constexpr int MI = BM / 32;
    constexpr int NI = BN / 32;
    const int lane = tid & 63;
    const int ln   = lane & 15;
    const int quad = lane >> 4;
    const int wv   = tid >> 6;
    const int wm   = (wv & 1) * (BM / 2);
    const int wn   = (wv >> 1) * (BN / 2);

    f32x4 acc[MI][NI];
    #pragma unroll
    for (int i = 0; i < MI; ++i)
        #pragma unroll
        for (int j = 0; j < NI; ++j) acc[i][j] = (f32x4){0.f, 0.f, 0.f, 0.f};

    auto stage = [&](int bufi, int k0) {
        u16* As = AsB + bufi * (BM * 32);
        u16* Bs = BsB + bufi * (BN * 32);
        #pragma unroll
        for (int it = 0; it < BM / 64; ++it) {
            int flat = it * 256 + tid;
            gl_lds16(A + (size_t)(m0 + (flat >> 2)) * lda + k0 + ((flat & 3) << 3),
                     &As[flat * 8]);
        }
        #pragma unroll
        for (int it = 0; it < BN / 64; ++it) {
            int flat = it * 256 + tid;
            gl_lds16(Bt + (size_t)(n0 + (flat >> 2)) * K + k0 + ((flat & 3) << 3),
                     &Bs[flat * 8]);
        }
    };

    stage(0, 0);
    __syncthreads();

    int buf = 0;
    for (int k0 = 0; k0 < K; k0 += 32) {
        if (k0 + 32 < K) stage(buf ^ 1, k0 + 32);

        u16* As = AsB + buf * (BM * 32);
        u16* Bs = BsB + buf * (BN * 32);
        short8 af[MI], bfv[NI];
        #pragma unroll
        for (int mi = 0; mi < MI; ++mi)
            af[mi] = *(const short8*)(&As[(wm + mi * 16 + ln) * 32 + quad * 8]);
        #pragma unroll
        for (int ni = 0; ni < NI; ++ni)
            bfv[ni] = *(const short8*)(&Bs[(wn + ni * 16 + ln) * 32 + quad * 8]);
        #pragma unroll
        for (int mi = 0; mi < MI; ++mi)
            #pragma unroll
            for (int ni = 0; ni < NI; ++ni)
                acc[mi][ni] = __builtin_amdgcn_mfma_f32_16x16x32_bf16(af[mi], bfv[ni], acc[mi][ni], 0, 0, 0);

        __syncthreads();
        buf ^= 1;
    }

    float bb[NI];
    #pragma unroll
    for (int ni = 0; ni < NI; ++ni) bb[ni] = bias[n0 + wn + ni * 16 + ln];

    #pragma unroll
    for (int mi = 0; mi < MI; ++mi) {
        #pragma unroll
        for (int r = 0; r < 4; ++r) {
            const size_t row = (size_t)(m0 + wm + mi * 16 + quad * 4 + r);
            #pragma unroll
            for (int ni = 0; ni < NI; ++ni) {
                float v = (acc[mi][ni][r] + bb[ni]) * oscale;
                const size_t idx = row * N + n0 + wn + ni * 16 + ln;
                if (outf32) ((float*)Out)[idx] = v;
                else        ((u16*)Out)[idx]  = f2bf(v);
            }
        }
    }
}

template<int BM, int BN, bool OUTF32>
__global__ __launch_bounds__(256, 2)
void gemm_mfma(const u16* __restrict__ A, int lda,
               const u16* __restrict__ Bt,
               const float* __restrict__ bias,
               void* __restrict__ Out, int N, int K, float oscale)
{
    __shared__ __align__(16) u16 As[2 * BM * 32];
    __shared__ __align__(16) u16 Bs[2 * BN * 32];
    gemm_body<BM, BN>(As, Bs, A, lda, Bt, bias, Out, OUTF32, oscale,
                      N, K, blockIdx.y * BM, blockIdx.x * BN, threadIdx.x);
}

// merged qk + kv + q GEMMs (1056 blocks -> 4/CU); q output pre-scaled
__global__ __launch_bounds__(256, 2)
void gemm3(const u16* __restrict__ hb,
           const u16* __restrict__ wqkt, const float* __restrict__ bqk, u16* __restrict__ Zqk,
           const u16* __restrict__ wkvt, const float* __restrict__ bkv, u16* __restrict__ kvbb,
           const u16* __restrict__ wqt,  const float* __restrict__ bq,  u16* __restrict__ qb)
{
    __shared__ __align__(16) u16 As[2 * 4096];
    __shared__ __align__(16) u16 Bs[2 * 4096];
    int id = blockIdx.x;
    const u16* A; const u16* Bt; const float* bias; u16* Out; int N, K, bx, by;
    float osc = 1.0f;
    if (id < 288)      { A = hb;       Bt = wqkt; bias = bqk; Out = Zqk;  N = 1152; K = 1024; bx = id % 9;  by = id / 9; }
    else if (id < 800) { id -= 288; A = hb;       Bt = wkvt; bias = bkv; Out = kvbb; N = 2048; K = 512;  bx = id % 16; by = id / 16; }
    else               { id -= 800; A = hb + 512; Bt = wqt;  bias = bq;  Out = qb;   N = 1024; K = 512;  bx = id % 8;  by = id / 8; osc = SCALE2; }
    gemm_body<128, 128>(As, Bs, A, 1024, Bt, bias, Out, false, osc, N, K,
                        by * 128, bx * 128, threadIdx.x);
}

// ---------------------------------------------------------------------------
// Merged RoPE on Zqk (stride 1152): qRt (scaled by SCALE2) + kRt (unscaled)
// ---------------------------------------------------------------------------
__global__ void rope_bf(u16* __restrict__ Zqk)
{
    int idx = blockIdx.x * 256 + threadIdx.x;
    u16* p;
    int t;
    float e, osc;
    if (idx < M_ * 512) {
        int row = idx >> 9, pr = idx & 511;
        e = (-2.0f * (float)pr / 1024.0f) * 9.210340371976184f;
        p = Zqk + (size_t)row * 1152 + (pr << 1);
        t = row & (T_ - 1);
        osc = SCALE2;
    } else {
        int r = idx - M_ * 512;
        if (r >= M_ * 32) return;
        int row = r >> 5, pr = r & 31;
        e = (-2.0f * (float)pr / 64.0f) * 9.210340371976184f;
        p = Zqk + 1024 + (size_t)row * 1152 + (pr << 1);
        t = row & (T_ - 1);
        osc = 1.0f;
    }
    float theta = expf(e);
    float ang = (float)(t + 1) * theta;
    float s = sinf(ang), c = cosf(ang);
    float x1 = bf2f(p[0]);
    float x2 = bf2f(p[1]);
    p[0] = f2bf((x1 * c - x2 * s) * osc);
    p[1] = f2bf((x2 * c + x1 * s) * osc);
}

// ---------------------------------------------------------------------------
// MFMA flash attention v4: key-split (flash-decoding) for 2 blocks/CU.
// Grid (16,32) = 512 uniform blocks. Block (p = x&7, s = x>>3) runs two
// sequential segments: (qtA=p, key-half s) and (qtB=15-p, key-half 1-s)
// -> exactly 17 staged+computed tiles/block. Each segment writes an
// UNNORMALIZED partial (O fp32, m, l); attn_merge combines halves.
// Q is pre-scaled by SCALE2 -> softmax in exp2 domain with no extra mul.
// ---------------------------------------------------------------------------
#define KROW  136   // 128 + 8 pad
#define VROW  72    // 64 + 8
#define PROW  72    // 64 + 8

__global__ __launch_bounds__(256, 2)
void attn_mfma(const u16* __restrict__ qh,
               const u16* __restrict__ qR, int qRstride,
               const u16* __restrict__ kv,
               const u16* __restrict__ kR, int kRstride,
               float* __restrict__ Opart,       // [1024][128][64] fp32
               float* __restrict__ MLpart)      // [1024][128][2]  fp32
{
    __shared__ __align__(16) u16 Ks[2][64 * KROW];
    __shared__ __align__(16) u16 Vt[2][64 * VROW];
    __shared__ __align__(16) u16 Ps[4 * 32 * PROW];

    const int tid  = threadIdx.x;
    const int lane = tid & 63;
    const int ln   = lane & 15;
    const int quad = lane >> 4;
    const int wv   = tid >> 6;
    const int bh   = blockIdx.y;
    const int b    = bh >> 4;
    const int h    = bh & 15;
    const int bT   = b * T_;
    const int p    = blockIdx.x & 7;
    const int s    = blockIdx.x >> 3;

    // staging pipeline registers
    short8 kreg[4];
    u16    vreg[2][8];

    auto prefetch = [&](int kt) {
        const int kbase = bT + (kt << 6);
        #pragma unroll
        for (int it = 0; it < 4; ++it) {
            int flat = tid + (it << 8);
            int j    = flat >> 4;
            int c8   = (flat & 15) << 3;
            const u16* src = (c8 < 64)
                ? (kv + (size_t)(kbase + j) * (2 * C_) + h * 64 + c8)
                : (kR + (size_t)(kbase + j) * kRstride + (c8 - 64));
            kreg[it] = *(const short8*)src;
        }
        #pragma unroll
        for (int it = 0; it < 2; ++it) {
            int flat = tid + (it << 8);
            int dv   = flat & 63;
            int kg   = flat >> 6;
            const u16* vs = kv + (size_t)(kbase + kg * 8) * (2 * C_) + C_ + h * 64 + dv;
            #pragma unroll
            for (int j = 0; j < 8; ++j) vreg[it][j] = vs[(size_t)j * (2 * C_)];
        }
    };
    auto lds_write = [&](int bufi) {
        #pragma unroll
        for (int it = 0; it < 4; ++it) {
            int flat = tid + (it << 8);
            int j    = flat >> 4;
            int c8   = (flat & 15) << 3;
            *(short8*)(&Ks[bufi][j * KROW + c8]) = kreg[it];
        }
        #pragma unroll
        for (int it = 0; it < 2; ++it) {
            int flat = tid + (it << 8);
            int dv   = flat & 63;
            int kg   = flat >> 6;
            short8 vv;
            #pragma unroll
            for (int j = 0; j < 8; ++j) vv[j] = (short)vreg[it][j];
            *(short8*)(&Vt[bufi][dv * VROW + kg * 8]) = vv;
        }
    };

    const int qts[2]    = { p, 15 - p };
    const int halves[2] = { s, 1 - s };

    for (int seg = 0; seg < 2; ++seg) {
        const int qt   = qts[seg];
        const int hf   = halves[seg];
        const int n    = 2 * qt + 2;
        const int ktlo = hf ? (n >> 1) : 0;
        const int kthi = hf ? n : (n >> 1);
        const int part = ((bh * 16 + qt) << 1) + hf;
        const int wq0  = qt * 128 + wv * 32;

        // Q fragments (B-operand), pre-scaled
        short8 aq[2][4];
        #pragma unroll
        for (int ni = 0; ni < 2; ++ni) {
            const size_t row = (size_t)(bT + wq0 + ni * 16 + ln);
            #pragma unroll
            for (int kk = 0; kk < 4; ++kk) {
                const int col = kk * 32 + quad * 8;
                const u16* src = (kk < 2)
                    ? (qh + row * C_ + h * 64 + col)
                    : (qR + row * qRstride + h * 64 + (col - 64));
                aq[ni][kk] = *(const short8*)src;
            }
        }

        f32x4 O[2][4];
        float m_run[2], l_run[2];
        #pragma unroll
        for (int ni = 0; ni < 2; ++ni) {
            m_run[ni] = -1e30f;
            l_run[ni] = 0.f;
            #pragma unroll
            for (int mt = 0; mt < 4; ++mt) O[ni][mt] = (f32x4){0.f, 0.f, 0.f, 0.f};
        }

        prefetch(ktlo);
        lds_write(0);
        if (ktlo + 1 < kthi) prefetch(ktlo + 1);
        __syncthreads();

        for (int kt = ktlo; kt < kthi; ++kt) {
            const int cur = (kt - ktlo) & 1;
            if (kt + 1 < kthi) lds_write(cur ^ 1);
            if (kt + 2 < kthi) prefetch(kt + 2);

            const int k0 = kt << 6;
            if (k0 <= wq0 + 31) {
                // ---- S^T = K Q^T ----
                f32x4 S[2][4];
                #pragma unroll
                for (int ni = 0; ni < 2; ++ni)
                    #pragma unroll
                    for (int mi = 0; mi < 4; ++mi)
                        S[ni][mi] = (f32x4){0.f, 0.f, 0.f, 0.f};

                #pragma unroll
                for (int kk = 0; kk < 4; ++kk) {
                    #pragma unroll
                    for (int mi = 0; mi < 4; ++mi) {
                        short8 ak = *(const short8*)(&Ks[cur][(mi * 16 + ln) * KROW + kk * 32 + quad * 8]);
                        S[0][mi] = __builtin_amdgcn_mfma_f32_16x16x32_bf16(ak, aq[0][kk], S[0][mi], 0, 0, 0);
                        S[1][mi] = __builtin_amdgcn_mfma_f32_16x16x32_bf16(ak, aq[1][kk], S[1][mi], 0, 0, 0);
                    }
                }

                const bool full = (k0 + 63) <= wq0;

                #pragma unroll
                for (int ni = 0; ni < 2; ++ni) {
                    const int qg = wq0 + ni * 16 + ln;
                    float sv[16];
                    float mloc = -1e30f;
                    #pragma unroll
                    for (int mi = 0; mi < 4; ++mi)
                        #pragma unroll
                        for (int r = 0; r < 4; ++r) {
                            float sc = S[ni][mi][r];
                            if (!full) {
                                int key = k0 + mi * 16 + quad * 4 + r;
                                if (key > qg) sc = -1e30f;
                            }
                            sv[mi * 4 + r] = sc;
                            mloc = fmaxf(mloc, sc);
                        }
                    mloc = fmaxf(mloc, __shfl_xor(mloc, 16));
                    mloc = fmaxf(mloc, __shfl_xor(mloc, 32));
                    const float mold  = m_run[ni];
                    const float mnew  = fmaxf(mold, mloc);
                    const float alpha = exp2f(mold - mnew);
                    m_run[ni] = mnew;

                    float lsum = 0.f;
                    #pragma unroll
                    for (int mi = 0; mi < 4; ++mi) {
                        float p0 = exp2f(sv[mi * 4 + 0] - mnew);
                        float p1 = exp2f(sv[mi * 4 + 1] - mnew);
                        float p2 = exp2f(sv[mi * 4 + 2] - mnew);
                        float p3 = exp2f(sv[mi * 4 + 3] - mnew);
                        lsum += (p0 + p1) + (p2 + p3);
                        short4v pk;
                        pk[0] = (short)f2bf_fast(p0); pk[1] = (short)f2bf_fast(p1);
                        pk[2] = (short)f2bf_fast(p2); pk[3] = (short)f2bf_fast(p3);
                        *(short4v*)(&Ps[(wv * 32 + ni * 16 + ln) * PROW + mi * 16 + quad * 4]) = pk;
                    }
                    lsum += __shfl_xor(lsum, 16);
                    lsum += __shfl_xor(lsum, 32);
                    l_run[ni] = l_run[ni] * alpha + lsum;

                    #pragma unroll
                    for (int mt = 0; mt < 4; ++mt) {
                        O[ni][mt][0] *= alpha;
                        O[ni][mt][1] *= alpha;
                        O[ni][mt][2] *= alpha;
                        O[ni][mt][3] *= alpha;
                    }
                }

                asm volatile("s_waitcnt lgkmcnt(0)" ::: "memory");

                // ---- O^T += V^T P ----
                #pragma unroll
                for (int c = 0; c < 2; ++c) {
                    short8 pb0 = *(const short8*)(&Ps[(wv * 32 +  0 + ln) * PROW + c * 32 + quad * 8]);
                    short8 pb1 = *(const short8*)(&Ps[(wv * 32 + 16 + ln) * PROW + c * 32 + quad * 8]);
                    #pragma unroll
                    for (int mt = 0; mt < 4; ++mt) {
                        short8 av = *(const short8*)(&Vt[cur][(mt * 16 + ln) * VROW + c * 32 + quad * 8]);
                        O[0][mt] = __builtin_amdgcn_mfma_f32_16x16x32_bf16(av, pb0, O[0][mt], 0, 0, 0);
                        O[1][mt] = __builtin_amdgcn_mfma_f32_16x16x32_bf16(av, pb1, O[1][mt], 0, 0, 0);
                    }
                }
            }
            __syncthreads();
        }

        // ---- write unnormalized partial ----
        #pragma unroll
        for (int ni = 0; ni < 2; ++ni) {
            const int qlocal = wv * 32 + ni * 16 + ln;
            float* dst = Opart + ((size_t)part * 128 + qlocal) * 64;
            #pragma unroll
            for (int mt = 0; mt < 4; ++mt)
                *(f32x4*)(dst + mt * 16 + quad * 4) = O[ni][mt];
            if (quad == 0) {
                float2* ml = (float2*)MLpart;
                ml[part * 128 + qlocal] = make_float2(m_run[ni], l_run[ni]);
            }
        }
    }
}

// ---------------------------------------------------------------------------
// Merge the two key-half partials -> attnb (bf16, [B*T][C] head-interleaved)
// ---------------------------------------------------------------------------
__global__ void attn_merge(const float* __restrict__ Opart,
                           const float* __restrict__ MLpart,
                           u16* __restrict__ out)
{
    int g = blockIdx.x * 256 + threadIdx.x;    // 1,048,576 threads
    int row    = g >> 4;                       // (bh*16+qt)*128 + qlocal
    int c4     = (g & 15) << 2;
    int bhqt   = row >> 7;
    int qlocal = row & 127;
    const float2* ml = (const float2*)MLpart;
    float2 ml0 = ml[(bhqt << 1) * 128 + qlocal];
    float2 ml1 = ml[((bhqt << 1) + 1) * 128 + qlocal];
    float m  = fmaxf(ml0.x, ml1.x);
    float a0 = exp2f(ml0.x - m);
    float a1 = exp2f(ml1.x - m);
    float inv = 1.0f / (ml0.y * a0 + ml1.y * a1);
    const float4 o0 = *(const float4*)(Opart + ((size_t)(bhqt << 1) * 128 + qlocal) * 64 + c4);
    const float4 o1 = *(const float4*)(Opart + ((size_t)((bhqt << 1) + 1) * 128 + qlocal) * 64 + c4);
    int bh = bhqt >> 4, qt = bhqt & 15;
    int b = bh >> 4, h = bh & 15;
    size_t orow = (size_t)(b * T_ + qt * 128 + qlocal);
    short4v o;
    o[0] = (short)f2bf((o0.x * a0 + o1.x * a1) * inv);
    o[1] = (short)f2bf((o0.y * a0 + o1.y * a1) * inv);
    o[2] = (short)f2bf((o0.z * a0 + o1.z * a1) * inv);
    o[3] = (short)f2bf((o0.w * a0 + o1.w * a1) * inv);
    *(short4v*)(out + orow * C_ + h * 64 + c4) = o;
}

// ---------------------------------------------------------------------------
extern "C" void kernel_launch(void* const* d_in, const int* in_sizes, int n_in,
                              void* d_out, int out_size, void* d_ws, size_t ws_size,
                              hipStream_t stream)
{
    const float* x   = (const float*)d_in[0];
    const float* w1  = (const float*)d_in[1];
    const float* b1  = (const float*)d_in[2];
    const float* wkr = (const float*)d_in[3];
    const float* bkr = (const float*)d_in[4];
    const float* wqr = (const float*)d_in[5];
    const float* bqr = (const float*)d_in[6];
    const float* wkv = (const float*)d_in[7];
    const float* bkv = (const float*)d_in[8];
    const float* wq  = (const float*)d_in[9];
    const float* bq  = (const float*)d_in[10];
    const float* wo  = (const float*)d_in[11];
    const float* bo  = (const float*)d_in[12];
    float* out = (float*)d_out;

    // workspace (u16 units)
    u16* ws    = (u16*)d_ws;
    u16* buf0  = ws;                      // xb, later qb     (4096*1024)
    u16* buf1  = buf0 + 4194304;          // hb, later attnb  (4096*1024)
    u16* Zqk   = buf1 + 4194304;          // 4096*1152
    u16* kvbb  = Zqk  + 4718592;          // 4096*2048
    u16* w1t   = kvbb + 8388608;          // 1024*1024
    u16* wqkt  = w1t  + 1048576;          // 1152*1024
    u16* wkvt  = wqkt + 1179648;          // 2048*512
    u16* wqt   = wkvt + 1048576;          // 1024*512
    u16* wot   = wqt  + 524288;           // 1024*1024
    float* bqk   = (float*)(wot + 1048576);   // 1280 floats (1152 used)
    float* Opart = bqk + 1280;                // 1024*128*64 fp32 (33.5 MB)
    float* MLprt = Opart + 8388608;           // 1024*128*2  fp32

    u16* xb    = buf0;
    u16* qb    = buf0;
    u16* hb    = buf1;
    u16* attnb = buf1;

    dim3 blk(256);

    prep_all<<<8769, blk, 0, stream>>>(x, xb, w1, wqr, wkr, wkv, wq, wo,
                                       w1t, wqkt, wkvt, wqt, wot,
                                       bqr, bkr, bqk);

    // h = x @ w1 + b1   [4096,1024]  (512 blocks -> 2/CU)
    gemm_mfma<128, 64, false><<<dim3(16, 32), blk, 0, stream>>>(xb, 1024, w1t, b1, hb, 1024, 1024, 1.0f);
    // fused: Zqk / kv / q (q pre-scaled by SCALE2)
    gemm3<<<1056, blk, 0, stream>>>(hb, wqkt, bqk, Zqk, wkvt, bkv, kvbb, wqt, bq, qb);
    // rope (qRt scaled, kRt unscaled)
    rope_bf<<<(M_ * 544 + 255) / 256, blk, 0, stream>>>(Zqk);
    // attention partials (512 uniform blocks -> 2/CU)
    attn_mfma<<<dim3(16, 32), blk, 0, stream>>>(qb, Zqk, 1152, kvbb, Zqk + 1024, 1152, Opart, MLprt);
    // merge halves -> attnb
    attn_merge<<<4096, blk, 0, stream>>>(Opart, MLprt, attnb);
    // out = attn @ wo + bo   [4096,1024] fp32  (512 blocks -> 2/CU)
    gemm_mfma<128, 64, true><<<dim3(16, 32), blk, 0, stream>>>(attnb, 1024, wot, bo, out, 1024, 1024, 1.0f);
}